// Round 6
// baseline (1228.174 us; speedup 1.0000x reference)
//
#include <hip/hip_runtime.h>
#include <math.h>

// ---------------------------------------------------------------------------
// B=2, S=4096, C=1024, H=16, Dh=64, G=3, Ms=256, NRF=256, L=64
// Round 6: r5 + vectorized GEMM epilogue (LDS-transposed, full-line stores).
// K-loop and all non-GEMM kernels identical to round 5.
// ---------------------------------------------------------------------------

using f32x4 = __attribute__((ext_vector_type(4))) float;
using s16x8 = __attribute__((ext_vector_type(8))) short;

__device__ __forceinline__ unsigned short f2bf(float x) {
  unsigned u = __float_as_uint(x);
  unsigned r = u + 0x7fffu + ((u >> 16) & 1u);
  return (unsigned short)(r >> 16);
}
__device__ __forceinline__ float bf2f(unsigned short h) {
  return __uint_as_float(((unsigned)h) << 16);
}

// ======================== f32 -> bf16 hi/lo splitter ========================
__global__ __launch_bounds__(256) void split_prep_kernel(
    const float* __restrict__ in, unsigned short* __restrict__ ohi,
    unsigned short* __restrict__ olo, int n8)
{
  const int i = blockIdx.x * 256 + threadIdx.x;
  if (i >= n8) return;
  const float4 f0 = ((const float4*)in)[i * 2];
  const float4 f1 = ((const float4*)in)[i * 2 + 1];
  const float v[8] = {f0.x, f0.y, f0.z, f0.w, f1.x, f1.y, f1.z, f1.w};
  s16x8 hi, lo;
  #pragma unroll
  for (int u = 0; u < 8; ++u) {
    const unsigned short hh = f2bf(v[u]);
    hi[u] = (short)hh;
    lo[u] = (short)f2bf(v[u] - bf2f(hh));
  }
  ((s16x8*)ohi)[i] = hi;
  ((s16x8*)olo)[i] = lo;
}

// ======================== weight transpose + convert ========================
template<int WM>  // 0 conv(3i, split) 1 rff(9 z=i*3+g, split) 2 proj(3i) 3 out_w
__global__ __launch_bounds__(256) void wconv_kernel(
    const float* __restrict__ in0, unsigned short* __restrict__ ohi,
    unsigned short* __restrict__ olo)
{
  int K, N;
  const float* in;
  unsigned short *oh, *ol = nullptr;
  const int z = blockIdx.z;
  if constexpr (WM == 0) {
    K = 768; N = 1024;
    in = in0 + (size_t)z * 786432;
    oh = ohi + (size_t)z * 786432; ol = olo + (size_t)z * 786432;
  } else if constexpr (WM == 1) {
    K = 1024; N = 256;
    const int i = z / 3, g = z % 3;
    in = in0 + (size_t)i * 786432 + (size_t)g * 262144;
    oh = ohi + (size_t)i * 786432 + (size_t)g * 262144;
    ol = olo + (size_t)i * 786432 + (size_t)g * 262144;
  } else if constexpr (WM == 2) {
    K = 768; N = 1024;
    in = in0 + (size_t)z * 786432; oh = ohi + (size_t)z * 786432;
  } else {
    K = 1024; N = 1024; in = in0; oh = ohi;
  }
  const int k0 = blockIdx.x * 64, n0 = blockIdx.y * 64;
  __shared__ float t[64][65];
  const int tid = threadIdx.x, tn = tid & 63, tr = tid >> 6;
  #pragma unroll 4
  for (int p = 0; p < 16; ++p) {
    const int kk = p * 4 + tr;
    t[kk][tn] = in[(size_t)(k0 + kk) * N + n0 + tn];
  }
  __syncthreads();
  #pragma unroll 4
  for (int p = 0; p < 16; ++p) {
    const int nn = p * 4 + tr;
    const float v = t[tn][nn];
    const unsigned short hi = f2bf(v);
    oh[(size_t)(n0 + nn) * K + k0 + tn] = hi;
    if constexpr (WM <= 1)
      ol[(size_t)(n0 + nn) * K + k0 + tn] = f2bf(v - bf2f(hi));
  }
}

// omega [64][256] f32 -> omegaT [256][64] bf16 hi/lo
__global__ __launch_bounds__(256) void omega_prep_kernel(
    const float* __restrict__ omega, unsigned short* __restrict__ oThi,
    unsigned short* __restrict__ oTlo)
{
  const int idx = blockIdx.x * 256 + threadIdx.x;  // 16384
  const int m = idx >> 6, d = idx & 63;
  const float v = omega[d * 256 + m];
  const unsigned short hi = f2bf(v);
  oThi[idx] = hi;
  oTlo[idx] = f2bf(v - bf2f(hi));
}

// V [8192][1024] f32 -> VT[bh][80][4096] bf16 (rows 0..63 = V^T per head)
__global__ __launch_bounds__(256) void vt_kernel(
    const float* __restrict__ V, unsigned short* __restrict__ VT)
{
  const int bh = blockIdx.x, sb = blockIdx.y;
  const int b = bh >> 4, h = bh & 15;
  __shared__ float t[64][65];
  const int tid = threadIdx.x, tn = tid & 63, tr = tid >> 6;
  #pragma unroll 4
  for (int p = 0; p < 16; ++p)
    t[p * 4 + tr][tn] =
        V[(size_t)(b * 4096 + sb * 64 + p * 4 + tr) * 1024 + h * 64 + tn];
  __syncthreads();
  #pragma unroll 4
  for (int p = 0; p < 16; ++p)
    VT[((size_t)bh * 80 + p * 4 + tr) * 4096 + sb * 64 + tn] =
        f2bf(t[tn][p * 4 + tr]);
}

// VT rows 64..79: row 64 = 1.0 (ksum column), rows 65..79 = 0
__global__ __launch_bounds__(256) void vt_fill_kernel(unsigned short* __restrict__ VT)
{
  const int idx = blockIdx.x * 256 + threadIdx.x;  // 32*16*4096
  const int s = idx & 4095, rr = (idx >> 12) & 15, bh = idx >> 16;
  VT[((size_t)bh * 80 + 64 + rr) * 4096 + s] = (rr == 0) ? 0x3F80 : 0;
}

// ======================== MFMA GEMM (all-bf16 operands) =====================
// 128x128 tile, BK=32, 256 threads (2x2 waves), 16x16x32 bf16 MFMA.
// Epilogue: per-wave LDS transpose, 16-row slices -> contiguous vector stores.
template<int MODE>
__global__ __launch_bounds__(256, MODE == 2 ? 4 : 3) void gemm_mfma(
    const unsigned short* __restrict__ Ahi, const unsigned short* __restrict__ Alo,
    const unsigned short* __restrict__ Bhig, const unsigned short* __restrict__ Blog,
    const float* __restrict__ bias,
    float* __restrict__ Cf, unsigned short* __restrict__ C1,
    unsigned short* __restrict__ C2,
    int M, int N, int K)
{
  constexpr bool SPLIT = (MODE <= 1);
  // staging needs SPLIT?32768:16384 ; epilogue reuse needs 4*4352=17408
  __shared__ alignas(16) char smem[SPLIT ? 32768 : 17408];
  char* const sAhi = smem;
  char* const sBhi = smem + (SPLIT ? 16384 : 8192);
  char* const sAlo = smem + 8192;
  char* const sBlo = smem + 24576;

  const int tid = threadIdx.x;
  const int n0 = blockIdx.x * 128;
  const int m0 = blockIdx.y * 128;

  const int sr = tid >> 1;          // staged row 0..127
  const int kh = (tid & 1) * 16;    // k offset 0/16 (elements)
  const int sw = ((sr >> 1) & 3) << 4;          // byte swizzle
  const int c0 = kh >> 3;                       // 16B chunk index 0 or 2
  const int db0 = sr * 64 + ((c0 * 16) ^ sw);   // BYTE offset
  const int db1 = sr * 64 + (((c0 + 1) * 16) ^ sw);

  const int lane = tid & 63, wid = tid >> 6;
  const int wr = wid >> 1, wc = wid & 1;
  const int fr = lane & 15, kc = lane >> 4;
  const int fsw = ((fr >> 1) & 3) << 4;

  f32x4 acc[4][4];
  #pragma unroll
  for (int i = 0; i < 4; ++i)
    #pragma unroll
    for (int j = 0; j < 4; ++j) acc[i][j] = f32x4{0.f, 0.f, 0.f, 0.f};

  for (int k0 = 0; k0 < K; k0 += 32) {
    s16x8 ah0, ah1, al0, al1, bh0, bh1, bl0, bl1;
    // ---- A global -> regs (bf16 direct) ----
    if constexpr (MODE == 0) {
      const int grow = m0 + sr;
      const int bb = grow >> 12, s = grow & 4095;
      const int t = k0 >> 8;
      const int ss = s + t - 1;
      const bool valid = ((unsigned)ss < 4096u);
      const int ci = (k0 & 255) + kh;
      const size_t off =
          ((size_t)(bb * 4096 + (valid ? ss : 0))) * 1024 + (n0 >> 8) * 256 + ci;
      if (valid) {
        ah0 = *(const s16x8*)(Ahi + off); ah1 = *(const s16x8*)(Ahi + off + 8);
        al0 = *(const s16x8*)(Alo + off); al1 = *(const s16x8*)(Alo + off + 8);
      } else {
        #pragma unroll
        for (int u = 0; u < 8; ++u) { ah0[u] = 0; ah1[u] = 0; al0[u] = 0; al1[u] = 0; }
      }
    } else {
      const size_t off = (size_t)(m0 + sr) * K + k0 + kh;
      ah0 = *(const s16x8*)(Ahi + off); ah1 = *(const s16x8*)(Ahi + off + 8);
      if constexpr (SPLIT) {
        al0 = *(const s16x8*)(Alo + off); al1 = *(const s16x8*)(Alo + off + 8);
      }
    }
    // ---- B global -> regs ----
    {
      const size_t off = (size_t)(n0 + sr) * K + k0 + kh;
      bh0 = *(const s16x8*)(Bhig + off); bh1 = *(const s16x8*)(Bhig + off + 8);
      if constexpr (SPLIT) {
        bl0 = *(const s16x8*)(Blog + off); bl1 = *(const s16x8*)(Blog + off + 8);
      }
    }
    __syncthreads();
    *(s16x8*)(sAhi + db0) = ah0; *(s16x8*)(sAhi + db1) = ah1;
    *(s16x8*)(sBhi + db0) = bh0; *(s16x8*)(sBhi + db1) = bh1;
    if constexpr (SPLIT) {
      *(s16x8*)(sAlo + db0) = al0; *(s16x8*)(sAlo + db1) = al1;
      *(s16x8*)(sBlo + db0) = bl0; *(s16x8*)(sBlo + db1) = bl1;
    }
    __syncthreads();

    s16x8 Af[4], Al[4], Bf[4], Bl[4];
    #pragma unroll
    for (int i = 0; i < 4; ++i) {
      const int off = (wr * 64 + i * 16 + fr) * 64 + ((kc * 16) ^ fsw);
      Af[i] = *(const s16x8*)(sAhi + off);
      if constexpr (SPLIT) Al[i] = *(const s16x8*)(sAlo + off);
    }
    #pragma unroll
    for (int j = 0; j < 4; ++j) {
      const int off = (wc * 64 + j * 16 + fr) * 64 + ((kc * 16) ^ fsw);
      Bf[j] = *(const s16x8*)(sBhi + off);
      if constexpr (SPLIT) Bl[j] = *(const s16x8*)(sBlo + off);
    }
    #pragma unroll
    for (int i = 0; i < 4; ++i)
      #pragma unroll
      for (int j = 0; j < 4; ++j) {
        acc[i][j] = __builtin_amdgcn_mfma_f32_16x16x32_bf16(Af[i], Bf[j], acc[i][j], 0, 0, 0);
        if constexpr (SPLIT) {
          acc[i][j] = __builtin_amdgcn_mfma_f32_16x16x32_bf16(Af[i], Bl[j], acc[i][j], 0, 0, 0);
          acc[i][j] = __builtin_amdgcn_mfma_f32_16x16x32_bf16(Al[i], Bf[j], acc[i][j], 0, 0, 0);
        }
      }
  }

  // ---- epilogue: LDS transpose (16-row slices), contiguous vector stores ----
  float* const epi = (float*)smem + wid * 1088;   // 16 rows x stride 68
  const int lr = lane >> 2;                       // 0..15 row within slice
  const int lcq = (lane & 3) * 16;                // col quarter 0/16/32/48
  const int colb = n0 + wc * 64 + lcq;

  // per-lane bias (and rff scale), hoisted
  float bv[16];
  #pragma unroll
  for (int q = 0; q < 4; ++q) {
    const float4 b4 = *reinterpret_cast<const float4*>(bias + colb + q * 4);
    bv[q * 4 + 0] = b4.x; bv[q * 4 + 1] = b4.y;
    bv[q * 4 + 2] = b4.z; bv[q * 4 + 3] = b4.w;
  }
  float sg = 1.0f;
  if constexpr (MODE == 1) {
    const int g = colb >> 8;
    sg = (g == 0) ? 1.0f : ((g == 1) ? 1.41421356237309515f : 2.0f);
  }

  #pragma unroll
  for (int i = 0; i < 4; ++i) {
    __syncthreads();
    #pragma unroll
    for (int j = 0; j < 4; ++j)
      #pragma unroll
      for (int rr = 0; rr < 4; ++rr)
        epi[(kc * 4 + rr) * 68 + j * 16 + fr] = acc[i][j][rr];
    __syncthreads();

    float vals[16];
    #pragma unroll
    for (int q = 0; q < 4; ++q) {
      const f32x4 v4 = *(const f32x4*)(epi + lr * 68 + lcq + q * 4);
      vals[q * 4 + 0] = v4[0]; vals[q * 4 + 1] = v4[1];
      vals[q * 4 + 2] = v4[2]; vals[q * 4 + 3] = v4[3];
    }
    const int row = m0 + wr * 64 + i * 16 + lr;
    const size_t cbase = (size_t)row * N + colb;
    if constexpr (MODE == 0) {
      s16x8 hi0, hi1, lo0, lo1;
      #pragma unroll
      for (int u = 0; u < 16; ++u) {
        const float hv = vals[u] + bv[u];
        const unsigned short hh = f2bf(hv);
        const unsigned short ll = f2bf(hv - bf2f(hh));
        if (u < 8) { hi0[u] = (short)hh; lo0[u] = (short)ll; }
        else       { hi1[u - 8] = (short)hh; lo1[u - 8] = (short)ll; }
      }
      *(s16x8*)(C1 + cbase) = hi0; *(s16x8*)(C1 + cbase + 8) = hi1;
      *(s16x8*)(C2 + cbase) = lo0; *(s16x8*)(C2 + cbase + 8) = lo1;
    } else if constexpr (MODE == 1) {
      s16x8 z0, z1;
      #pragma unroll
      for (int u = 0; u < 16; ++u) {
        const float z = cosf(vals[u] * sg + bv[u]) * 0.08838834764831845f;
        if (u < 8) z0[u] = (short)f2bf(z); else z1[u - 8] = (short)f2bf(z);
      }
      *(s16x8*)(C1 + cbase) = z0; *(s16x8*)(C1 + cbase + 8) = z1;
    } else {
      #pragma unroll
      for (int q = 0; q < 4; ++q) {
        f32x4 o;
        #pragma unroll
        for (int u = 0; u < 4; ++u) o[u] = vals[q * 4 + u] + bv[q * 4 + u];
        *(f32x4*)(Cf + cbase + q * 4) = o;
      }
    }
  }
}

// ======================== RoPE table + apply ================================
__global__ __launch_bounds__(256) void rope_table_kernel(float2* __restrict__ tab)
{
  const int idx = blockIdx.x * 256 + threadIdx.x;
  const int j = idx & 31, s = idx >> 5;
  const double inv = pow(10000.0, -(double)j * (1.0 / 32.0));
  double sd, cd;
  sincos((double)s * inv, &sd, &cd);
  tab[idx] = make_float2((float)cd, (float)sd);
}

__global__ __launch_bounds__(256) void rope_apply_kernel(
    const float2* __restrict__ tab, float* __restrict__ Q, float* __restrict__ Kb)
{
  const int idx = blockIdx.x * 256 + threadIdx.x;
  const int j = idx & 31;
  const int h = (idx >> 5) & 15;
  const int s = (idx >> 9) & 4095;
  const int b = idx >> 21;
  const float2 cs = tab[(s << 5) | j];
  const float snv = cs.y, csv = cs.x;
  const size_t base = ((size_t)(b * 4096 + s)) * 1024 + h * 64 + j;
  const float q0 = Q[base], q1 = Q[base + 32];
  Q[base]      = q0 * csv - q1 * snv;
  Q[base + 32] = q1 * csv + q0 * snv;
  const float k0 = Kb[base], k1 = Kb[base + 32];
  Kb[base]      = k0 * csv - k1 * snv;
  Kb[base + 32] = k1 * csv + k0 * snv;
}

// ======================== Nystrom RBF features ==============================
__global__ __launch_bounds__(256) void nystrom_kernel(
    const float* __restrict__ Kb, const float* __restrict__ lm,
    float* __restrict__ kny)
{
  __shared__ float lmT[64][65];
  __shared__ float lnorm[64];
  const int tid = threadIdx.x;
  for (int idx = tid; idx < 4096; idx += 256)
    lmT[idx & 63][idx >> 6] = lm[idx];
  if (tid < 64) {
    float s = 0.f;
    #pragma unroll
    for (int d = 0; d < 64; ++d) { const float v = lm[tid * 64 + d]; s = fmaf(v, v, s); }
    lnorm[tid] = s;
  }
  __syncthreads();
  const int lane = tid & 63;
  const int nw = gridDim.x * 4;
  for (int row = blockIdx.x * 4 + (tid >> 6); row < 131072; row += nw) {
    const float kd = Kb[(size_t)row * 64 + lane];
    float nk = kd * kd;
    #pragma unroll
    for (int o = 32; o > 0; o >>= 1) nk += __shfl_xor(nk, o, 64);
    float dot = 0.f;
    #pragma unroll
    for (int d = 0; d < 64; ++d) dot = fmaf(__shfl(kd, d, 64), lmT[d][lane], dot);
    kny[(size_t)row * 64 + lane] = __expf((2.f * dot - nk - lnorm[lane]) * 0.015625f);
  }
}

// ======================== FAVOR-K (MFMA) ====================================
__global__ __launch_bounds__(512) void favor_k_mfma(
    const float* __restrict__ kny,
    const unsigned short* __restrict__ oThi, const unsigned short* __restrict__ oTlo,
    const unsigned short* __restrict__ VT, float* __restrict__ KVp)
{
  const int bid = blockIdx.x;
  const int bh = bid >> 3, chunk = bid & 7;
  const int b = bh >> 4, h = bh & 15;
  const int s0 = chunk * 512;
  const int tid = threadIdx.x, lane = tid & 63, wid = tid >> 6;
  const int fr = lane & 15, kc = lane >> 4;
  const int m0w = wid * 32;

  __shared__ unsigned short P[256][40];
  __shared__ float T[8][32][84];

  s16x8 whi[2][2], wlo[2][2];
  #pragma unroll
  for (int c = 0; c < 2; ++c)
    #pragma unroll
    for (int ks = 0; ks < 2; ++ks) {
      const size_t off = (size_t)(m0w + c * 16 + fr) * 64 + ks * 32 + kc * 8;
      whi[c][ks] = *(const s16x8*)(oThi + off);
      wlo[c][ks] = *(const s16x8*)(oTlo + off);
    }

  f32x4 acc2[2][5];
  #pragma unroll
  for (int i = 0; i < 2; ++i)
    #pragma unroll
    for (int j = 0; j < 5; ++j) acc2[i][j] = f32x4{0.f, 0.f, 0.f, 0.f};

  for (int st = 0; st < 512; st += 32) {
    s16x8 ahi[2][2], alo[2][2];
    float nrm[2];
    #pragma unroll
    for (int r = 0; r < 2; ++r) {
      float part = 0.f;
      #pragma unroll
      for (int ks = 0; ks < 2; ++ks) {
        const float* ap = kny +
            ((size_t)((b * 4096 + s0 + st + r * 16 + fr) * 16 + h)) * 64 + ks * 32 + kc * 8;
        const float4 f0 = ((const float4*)ap)[0];
        const float4 f1 = ((const float4*)ap)[1];
        float v[8] = {f0.x, f0.y, f0.z, f0.w, f1.x, f1.y, f1.z, f1.w};
        #pragma unroll
        for (int u = 0; u < 8; ++u) {
          part = fmaf(v[u], v[u], part);
          const unsigned short hh = f2bf(v[u]);
          ahi[r][ks][u] = (short)hh;
          alo[r][ks][u] = (short)f2bf(v[u] - bf2f(hh));
        }
      }
      part += __shfl_xor(part, 16);
      part += __shfl_xor(part, 32);
      nrm[r] = 0.5f * part;
    }
    __syncthreads();
    #pragma unroll
    for (int r = 0; r < 2; ++r)
      #pragma unroll
      for (int c = 0; c < 2; ++c) {
        f32x4 s1 = f32x4{0.f, 0.f, 0.f, 0.f};
        #pragma unroll
        for (int ks = 0; ks < 2; ++ks) {
          s1 = __builtin_amdgcn_mfma_f32_16x16x32_bf16(alo[r][ks], whi[c][ks], s1, 0, 0, 0);
          s1 = __builtin_amdgcn_mfma_f32_16x16x32_bf16(ahi[r][ks], wlo[c][ks], s1, 0, 0, 0);
          s1 = __builtin_amdgcn_mfma_f32_16x16x32_bf16(ahi[r][ks], whi[c][ks], s1, 0, 0, 0);
        }
        #pragma unroll
        for (int reg = 0; reg < 4; ++reg) {
          const int sl = kc * 4 + reg;
          const float nn = __shfl(nrm[r], sl);
          const float p = __expf(s1[reg] - nn - 2.772588722239781f);
          P[m0w + c * 16 + fr][r * 16 + sl] = f2bf(p);
        }
      }
    __syncthreads();
    s16x8 b2[5];
    #pragma unroll
    for (int nf = 0; nf < 5; ++nf)
      b2[nf] = *(const s16x8*)(VT + ((size_t)bh * 80 + nf * 16 + fr) * 4096 +
                               s0 + st + kc * 8);
    #pragma unroll
    for (int mf = 0; mf < 2; ++mf) {
      const s16x8 a2 = *(const s16x8*)&P[m0w + mf * 16 + fr][kc * 8];
      #pragma unroll
      for (int nf = 0; nf < 5; ++nf)
        acc2[mf][nf] = __builtin_amdgcn_mfma_f32_16x16x32_bf16(a2, b2[nf], acc2[mf][nf], 0, 0, 0);
    }
  }
  #pragma unroll
  for (int mf = 0; mf < 2; ++mf)
    #pragma unroll
    for (int nf = 0; nf < 5; ++nf)
      #pragma unroll
      for (int reg = 0; reg < 4; ++reg)
        T[wid][mf * 16 + kc * 4 + reg][nf * 16 + fr] = acc2[mf][nf][reg];
  __syncthreads();
  #pragma unroll
  for (int i = 0; i < 40; ++i) {
    const int flat = i * 64 + lane;
    const int n = flat >> 5, ml = flat & 31;
    KVp[((size_t)bid * 80 + n) * 256 + m0w + ml] = T[wid][ml][n];
  }
}

// ======================== reduce KVp -> KVXT bf16 ===========================
__global__ __launch_bounds__(256) void reduce_kvxt_kernel(
    const float* __restrict__ KVp, unsigned short* __restrict__ KVXT)
{
  const int bh = blockIdx.x;
  const int m = threadIdx.x;
  for (int n = 0; n < 80; ++n) {
    float s = 0.f;
    #pragma unroll
    for (int c = 0; c < 8; ++c)
      s += KVp[((size_t)(bh * 8 + c) * 80 + n) * 256 + m];
    KVXT[((size_t)bh * 80 + n) * 256 + m] = f2bf(s);
  }
}

// ======================== FAVOR-Q (MFMA) ====================================
__global__ __launch_bounds__(512) void favor_q_mfma(
    const float* __restrict__ Q,
    const unsigned short* __restrict__ oThi, const unsigned short* __restrict__ oTlo,
    const unsigned short* __restrict__ KVXT, unsigned short* __restrict__ O)
{
  const int bid = blockIdx.x;
  const int bh = bid >> 4, chunk = bid & 15;
  const int b = bh >> 4, h = bh & 15;
  const int s0 = chunk * 256;
  const int tid = threadIdx.x, lane = tid & 63, wid = tid >> 6;
  const int fr = lane & 15, kc = lane >> 4;
  const int ws0 = s0 + wid * 32;

  __shared__ unsigned short KX[80][264];
  __shared__ unsigned short P[8][32][66];

  for (int i = tid; i < 80 * 256; i += 512)
    KX[i >> 8][i & 255] = KVXT[(size_t)bh * 80 * 256 + i];
  __syncthreads();

  s16x8 ahi[2][2], alo[2][2];
  float nrm[2];
  #pragma unroll
  for (int r = 0; r < 2; ++r) {
    float part = 0.f;
    #pragma unroll
    for (int ks = 0; ks < 2; ++ks) {
      const float* ap = Q + ((size_t)(b * 4096 + ws0 + r * 16 + fr)) * 1024 +
                        h * 64 + ks * 32 + kc * 8;
      const float4 f0 = ((const float4*)ap)[0];
      const float4 f1 = ((const float4*)ap)[1];
      float v[8] = {f0.x, f0.y, f0.z, f0.w, f1.x, f1.y, f1.z, f1.w};
      #pragma unroll
      for (int u = 0; u < 8; ++u) {
        part = fmaf(v[u], v[u], part);
        const unsigned short hh = f2bf(v[u]);
        ahi[r][ks][u] = (short)hh;
        alo[r][ks][u] = (short)f2bf(v[u] - bf2f(hh));
      }
    }
    part += __shfl_xor(part, 16);
    part += __shfl_xor(part, 32);
    nrm[r] = 0.5f * part;
  }

  f32x4 acc2[2][5];
  #pragma unroll
  for (int i = 0; i < 2; ++i)
    #pragma unroll
    for (int j = 0; j < 5; ++j) acc2[i][j] = f32x4{0.f, 0.f, 0.f, 0.f};

  for (int mc = 0; mc < 4; ++mc) {
    __syncthreads();
    #pragma unroll
    for (int r = 0; r < 2; ++r)
      #pragma unroll
      for (int c = 0; c < 4; ++c) {
        f32x4 s1 = f32x4{0.f, 0.f, 0.f, 0.f};
        #pragma unroll
        for (int ks = 0; ks < 2; ++ks) {
          const size_t off = (size_t)(mc * 64 + c * 16 + fr) * 64 + ks * 32 + kc * 8;
          const s16x8 bh1 = *(const s16x8*)(oThi + off);
          const s16x8 bl1 = *(const s16x8*)(oTlo + off);
          s1 = __builtin_amdgcn_mfma_f32_16x16x32_bf16(alo[r][ks], bh1, s1, 0, 0, 0);
          s1 = __builtin_amdgcn_mfma_f32_16x16x32_bf16(ahi[r][ks], bl1, s1, 0, 0, 0);
          s1 = __builtin_amdgcn_mfma_f32_16x16x32_bf16(ahi[r][ks], bh1, s1, 0, 0, 0);
        }
        #pragma unroll
        for (int reg = 0; reg < 4; ++reg) {
          const int sl = kc * 4 + reg;
          const float nn = __shfl(nrm[r], sl);
          const float p = __expf(s1[reg] - nn - 2.772588722239781f);
          P[wid][r * 16 + sl][c * 16 + fr] = f2bf(p);
        }
      }
    __syncthreads();
    #pragma unroll
    for (int ks2 = 0; ks2 < 2; ++ks2) {
      s16x8 b2[5];
      #pragma unroll
      for (int nf = 0; nf < 5; ++nf)
        b2[nf] = *(const s16x8*)&KX[nf * 16 + fr][mc * 64 + ks2 * 32 + kc * 8];
      #pragma unroll
      for (int r = 0; r < 2; ++r) {
        const s16x8 a2 = *(const s16x8*)&P[wid][r * 16 + fr][ks2 * 32 + kc * 8];
        #pragma unroll
        for (int nf = 0; nf < 5; ++nf)
          acc2[r][nf] = __builtin_amdgcn_mfma_f32_16x16x32_bf16(a2, b2[nf], acc2[r][nf], 0, 0, 0);
      }
    }
  }
  #pragma unroll
  for (int r = 0; r < 2; ++r)
    #pragma unroll
    for (int reg = 0; reg < 4; ++reg) {
      const int s = ws0 + r * 16 + kc * 4 + reg;
      const float dv = __shfl(acc2[r][4][reg], lane & 48) + 1e-6f;
      #pragma unroll
      for (int nf = 0; nf < 4; ++nf)
        O[(size_t)(b * 4096 + s) * 1024 + h * 64 + nf * 16 + fr] =
            f2bf(acc2[r][nf][reg] / dv);
    }
}

// ======================== launcher ==========================================
extern "C" void kernel_launch(void* const* d_in, const int* in_sizes, int n_in,
                              void* d_out, int out_size, void* d_ws, size_t ws_size,
                              hipStream_t stream)
{
  const float* x      = (const float*)d_in[0];
  const float* conv_k = (const float*)d_in[1];
  const float* conv_b = (const float*)d_in[2];
  const float* rff_w  = (const float*)d_in[3];
  const float* rff_b  = (const float*)d_in[4];
  const float* proj_w = (const float*)d_in[5];
  const float* proj_b = (const float*)d_in[6];
  const float* omega  = (const float*)d_in[7];
  const float* lm     = (const float*)d_in[8];
  const float* out_w  = (const float*)d_in[9];
  const float* out_b  = (const float*)d_in[10];

  char* wsb = (char*)d_ws;
  size_t o = 0;
  auto alloc = [&](size_t bytes) {
    char* p = wsb + o;
    o = (o + bytes + 255) & ~(size_t)255;
    return p;
  };
  unsigned short* Wc_hi = (unsigned short*)alloc(4718592);
  unsigned short* Wc_lo = (unsigned short*)alloc(4718592);
  unsigned short* Wr_hi = (unsigned short*)alloc(4718592);
  unsigned short* Wr_lo = (unsigned short*)alloc(4718592);
  unsigned short* Wp    = (unsigned short*)alloc(4718592);
  unsigned short* Wo    = (unsigned short*)alloc(2097152);
  // R1: xhi/xlo during QKV loop; VT afterwards
  char* R1 = alloc(33554432);
  unsigned short* xhi = (unsigned short*)R1;
  unsigned short* xlo = (unsigned short*)(R1 + 16777216);
  unsigned short* VT  = (unsigned short*)R1;              // 20,971,520 B
  // R2: h hi/lo during loop; kny afterwards
  char* R2 = alloc(33554432);
  unsigned short* hhi = (unsigned short*)R2;
  unsigned short* hlo = (unsigned short*)(R2 + 16777216);
  float* kny = (float*)R2;                                // 33,554,432 B
  unsigned short* feats = (unsigned short*)alloc(12582912);
  float* Qb = (float*)alloc(33554432);
  float* Kb = (float*)alloc(33554432);
  float* Vb = (float*)alloc(33554432);
  float2* tab = (float2*)alloc(1048576);
  unsigned short* oThi = (unsigned short*)alloc(32768);
  unsigned short* oTlo = (unsigned short*)alloc(32768);
  // R3: KVp f32; Obf afterwards
  char* R3 = alloc(20971520);
  float* KVp = (float*)R3;
  unsigned short* Obf = (unsigned short*)R3;              // 16,777,216 B
  unsigned short* KVXT = (unsigned short*)alloc(1310720);

  dim3 blk(256);
  // prep: conversions & tables
  split_prep_kernel<<<4096, blk, 0, stream>>>(x, xhi, xlo, 1048576);
  wconv_kernel<0><<<dim3(12, 16, 3), blk, 0, stream>>>(conv_k, Wc_hi, Wc_lo);
  wconv_kernel<1><<<dim3(16, 4, 9),  blk, 0, stream>>>(rff_w, Wr_hi, Wr_lo);
  wconv_kernel<2><<<dim3(12, 16, 3), blk, 0, stream>>>(proj_w, Wp, nullptr);
  wconv_kernel<3><<<dim3(16, 16, 1), blk, 0, stream>>>(out_w, Wo, nullptr);
  omega_prep_kernel<<<64, blk, 0, stream>>>(omega, oThi, oTlo);
  rope_table_kernel<<<512, blk, 0, stream>>>(tab);

  float* qkv[3] = {Qb, Kb, Vb};
  for (int i = 0; i < 3; ++i) {
    gemm_mfma<0><<<dim3(8, 64), blk, 0, stream>>>(
        xhi, xlo, Wc_hi + (size_t)i * 786432, Wc_lo + (size_t)i * 786432,
        conv_b + i * 1024, nullptr, hhi, hlo, 8192, 1024, 768);
    gemm_mfma<1><<<dim3(6, 64), blk, 0, stream>>>(
        hhi, hlo, Wr_hi + (size_t)i * 786432, Wr_lo + (size_t)i * 786432,
        rff_b + i * 768, nullptr, feats, nullptr, 8192, 768, 1024);
    gemm_mfma<2><<<dim3(8, 64), blk, 0, stream>>>(
        feats, nullptr, Wp + (size_t)i * 786432, nullptr,
        proj_b + i * 1024, qkv[i], nullptr, nullptr, 8192, 1024, 768);
  }
  rope_apply_kernel<<<16384, blk, 0, stream>>>(tab, Qb, Kb);
  vt_kernel<<<dim3(32, 64), blk, 0, stream>>>(Vb, VT);
  vt_fill_kernel<<<8192, blk, 0, stream>>>(VT);
  nystrom_kernel<<<512, blk, 0, stream>>>(Kb, lm, kny);
  favor_k_mfma<<<256, dim3(512), 0, stream>>>(kny, oThi, oTlo, VT, KVp);
  reduce_kvxt_kernel<<<32, blk, 0, stream>>>(KVp, KVXT);
  favor_q_mfma<<<512, dim3(512), 0, stream>>>(Qb, oThi, oTlo, KVXT, Obf);
  gemm_mfma<2><<<dim3(8, 64), blk, 0, stream>>>(
      Obf, nullptr, Wo, nullptr, out_b, (float*)d_out, nullptr, nullptr,
      8192, 1024, 1024);
}

// Round 7
// 1162.652 us; speedup vs baseline: 1.0564x; 1.0564x over previous
//
#include <hip/hip_runtime.h>
#include <math.h>

// ---------------------------------------------------------------------------
// B=2, S=4096, C=1024, H=16, Dh=64, G=3, Ms=256, NRF=256, L=64
// Round 7: z-batched QKV GEMMs (9 dispatches -> 3), RoPE fused into proj
// epilogue, vt_fill folded into vt, round-5 scalar epilogue restored.
// ---------------------------------------------------------------------------

using f32x4 = __attribute__((ext_vector_type(4))) float;
using s16x8 = __attribute__((ext_vector_type(8))) short;

__device__ __forceinline__ unsigned short f2bf(float x) {
  unsigned u = __float_as_uint(x);
  unsigned r = u + 0x7fffu + ((u >> 16) & 1u);
  return (unsigned short)(r >> 16);
}
__device__ __forceinline__ float bf2f(unsigned short h) {
  return __uint_as_float(((unsigned)h) << 16);
}

// ======================== f32 -> bf16 hi/lo splitter ========================
__global__ __launch_bounds__(256) void split_prep_kernel(
    const float* __restrict__ in, unsigned short* __restrict__ ohi,
    unsigned short* __restrict__ olo, int n8)
{
  const int i = blockIdx.x * 256 + threadIdx.x;
  if (i >= n8) return;
  const float4 f0 = ((const float4*)in)[i * 2];
  const float4 f1 = ((const float4*)in)[i * 2 + 1];
  const float v[8] = {f0.x, f0.y, f0.z, f0.w, f1.x, f1.y, f1.z, f1.w};
  s16x8 hi, lo;
  #pragma unroll
  for (int u = 0; u < 8; ++u) {
    const unsigned short hh = f2bf(v[u]);
    hi[u] = (short)hh;
    lo[u] = (short)f2bf(v[u] - bf2f(hh));
  }
  ((s16x8*)ohi)[i] = hi;
  ((s16x8*)olo)[i] = lo;
}

// ======================== weight transpose + convert ========================
template<int WM>  // 0 conv(3i, split) 1 rff(9 z=i*3+g, split) 2 proj(3i) 3 out_w
__global__ __launch_bounds__(256) void wconv_kernel(
    const float* __restrict__ in0, unsigned short* __restrict__ ohi,
    unsigned short* __restrict__ olo)
{
  int K, N;
  const float* in;
  unsigned short *oh, *ol = nullptr;
  const int z = blockIdx.z;
  if constexpr (WM == 0) {
    K = 768; N = 1024;
    in = in0 + (size_t)z * 786432;
    oh = ohi + (size_t)z * 786432; ol = olo + (size_t)z * 786432;
  } else if constexpr (WM == 1) {
    K = 1024; N = 256;
    const int i = z / 3, g = z % 3;
    in = in0 + (size_t)i * 786432 + (size_t)g * 262144;
    oh = ohi + (size_t)i * 786432 + (size_t)g * 262144;
    ol = olo + (size_t)i * 786432 + (size_t)g * 262144;
  } else if constexpr (WM == 2) {
    K = 768; N = 1024;
    in = in0 + (size_t)z * 786432; oh = ohi + (size_t)z * 786432;
  } else {
    K = 1024; N = 1024; in = in0; oh = ohi;
  }
  const int k0 = blockIdx.x * 64, n0 = blockIdx.y * 64;
  __shared__ float t[64][65];
  const int tid = threadIdx.x, tn = tid & 63, tr = tid >> 6;
  #pragma unroll 4
  for (int p = 0; p < 16; ++p) {
    const int kk = p * 4 + tr;
    t[kk][tn] = in[(size_t)(k0 + kk) * N + n0 + tn];
  }
  __syncthreads();
  #pragma unroll 4
  for (int p = 0; p < 16; ++p) {
    const int nn = p * 4 + tr;
    const float v = t[tn][nn];
    const unsigned short hi = f2bf(v);
    oh[(size_t)(n0 + nn) * K + k0 + tn] = hi;
    if constexpr (WM <= 1)
      ol[(size_t)(n0 + nn) * K + k0 + tn] = f2bf(v - bf2f(hi));
  }
}

// omega [64][256] f32 -> omegaT [256][64] bf16 hi/lo
__global__ __launch_bounds__(256) void omega_prep_kernel(
    const float* __restrict__ omega, unsigned short* __restrict__ oThi,
    unsigned short* __restrict__ oTlo)
{
  const int idx = blockIdx.x * 256 + threadIdx.x;  // 16384
  const int m = idx >> 6, d = idx & 63;
  const float v = omega[d * 256 + m];
  const unsigned short hi = f2bf(v);
  oThi[idx] = hi;
  oTlo[idx] = f2bf(v - bf2f(hi));
}

// V [8192][1024] f32 -> VT[bh][80][4096] bf16; rows 64..79: ksum row + zeros
__global__ __launch_bounds__(256) void vt_kernel(
    const float* __restrict__ V, unsigned short* __restrict__ VT)
{
  const int bh = blockIdx.x, sb = blockIdx.y;
  const int b = bh >> 4, h = bh & 15;
  __shared__ float t[64][65];
  const int tid = threadIdx.x, tn = tid & 63, tr = tid >> 6;
  #pragma unroll 4
  for (int p = 0; p < 16; ++p)
    t[p * 4 + tr][tn] =
        V[(size_t)(b * 4096 + sb * 64 + p * 4 + tr) * 1024 + h * 64 + tn];
  __syncthreads();
  #pragma unroll 4
  for (int p = 0; p < 16; ++p)
    VT[((size_t)bh * 80 + p * 4 + tr) * 4096 + sb * 64 + tn] =
        f2bf(t[tn][p * 4 + tr]);
  // rows 64..79 (ones row for ksum, then zero pad)
  #pragma unroll
  for (int p = 0; p < 4; ++p) {
    const int rr = p * 4 + tr;
    VT[((size_t)bh * 80 + 64 + rr) * 4096 + sb * 64 + tn] =
        (rr == 0) ? 0x3F80 : 0;
  }
}

// ======================== MFMA GEMM (all-bf16 operands, z-batched) ==========
// 128x128 tile, BK=32, 256 threads (2x2 waves), 16x16x32 bf16 MFMA.
// MODE 0 conv (split, z: A=xhi/xlo im2col shared; epi -> h hi/lo bf16)
// MODE 1 rff  (split, z; epi: cos -> feats bf16)
// MODE 2 proj (plain, z; epi: +bias, fused RoPE for z<2 -> QKV f32)
// MODE 3 final(plain; epi: +bias -> f32)
template<int MODE>
__global__ __launch_bounds__(256, MODE >= 2 ? 4 : 3) void gemm_mfma(
    const unsigned short* __restrict__ Ahi, const unsigned short* __restrict__ Alo,
    const unsigned short* __restrict__ Bhig, const unsigned short* __restrict__ Blog,
    const float* __restrict__ bias, const float2* __restrict__ tab,
    float* __restrict__ Cf, unsigned short* __restrict__ C1,
    unsigned short* __restrict__ C2,
    int M, int N, int K)
{
  constexpr bool SPLIT = (MODE <= 1);
  __shared__ alignas(16) char smem[SPLIT ? 32768 : 16384];
  char* const sAhi = smem;
  char* const sBhi = smem + (SPLIT ? 16384 : 8192);
  char* const sAlo = smem + 8192;
  char* const sBlo = smem + 24576;

  const int z = (MODE <= 2) ? blockIdx.z : 0;
  // per-z operand offsets
  if constexpr (MODE == 0) {
    Bhig += (size_t)z * 786432; Blog += (size_t)z * 786432;
    bias += z * 1024;
    C1 += (size_t)z * 8388608; C2 += (size_t)z * 8388608;
  } else if constexpr (MODE == 1) {
    Ahi += (size_t)z * 8388608; Alo += (size_t)z * 8388608;
    Bhig += (size_t)z * 786432; Blog += (size_t)z * 786432;
    bias += z * 768;
    C1 += (size_t)z * 6291456;
  } else if constexpr (MODE == 2) {
    Ahi += (size_t)z * 6291456;
    Bhig += (size_t)z * 786432;
    bias += z * 1024;
    Cf += (size_t)z * 8388608;
  }

  const int tid = threadIdx.x;
  const int n0 = blockIdx.x * 128;
  const int m0 = blockIdx.y * 128;

  const int sr = tid >> 1;          // staged row 0..127
  const int kh = (tid & 1) * 16;    // k offset 0/16 (elements)
  const int sw = ((sr >> 1) & 3) << 4;          // byte swizzle
  const int c0 = kh >> 3;                       // 16B chunk index 0 or 2
  const int db0 = sr * 64 + ((c0 * 16) ^ sw);   // BYTE offset
  const int db1 = sr * 64 + (((c0 + 1) * 16) ^ sw);

  const int lane = tid & 63, wid = tid >> 6;
  const int wr = wid >> 1, wc = wid & 1;
  const int fr = lane & 15, kc = lane >> 4;
  const int fsw = ((fr >> 1) & 3) << 4;

  f32x4 acc[4][4];
  #pragma unroll
  for (int i = 0; i < 4; ++i)
    #pragma unroll
    for (int j = 0; j < 4; ++j) acc[i][j] = f32x4{0.f, 0.f, 0.f, 0.f};

  for (int k0 = 0; k0 < K; k0 += 32) {
    s16x8 ah0, ah1, al0, al1, bh0, bh1, bl0, bl1;
    // ---- A global -> regs (bf16 direct) ----
    if constexpr (MODE == 0) {
      const int grow = m0 + sr;
      const int bb = grow >> 12, s = grow & 4095;
      const int t = k0 >> 8;
      const int ss = s + t - 1;
      const bool valid = ((unsigned)ss < 4096u);
      const int ci = (k0 & 255) + kh;
      const size_t off =
          ((size_t)(bb * 4096 + (valid ? ss : 0))) * 1024 + (n0 >> 8) * 256 + ci;
      if (valid) {
        ah0 = *(const s16x8*)(Ahi + off); ah1 = *(const s16x8*)(Ahi + off + 8);
        al0 = *(const s16x8*)(Alo + off); al1 = *(const s16x8*)(Alo + off + 8);
      } else {
        #pragma unroll
        for (int u = 0; u < 8; ++u) { ah0[u] = 0; ah1[u] = 0; al0[u] = 0; al1[u] = 0; }
      }
    } else {
      const size_t off = (size_t)(m0 + sr) * K + k0 + kh;
      ah0 = *(const s16x8*)(Ahi + off); ah1 = *(const s16x8*)(Ahi + off + 8);
      if constexpr (SPLIT) {
        al0 = *(const s16x8*)(Alo + off); al1 = *(const s16x8*)(Alo + off + 8);
      }
    }
    // ---- B global -> regs ----
    {
      const size_t off = (size_t)(n0 + sr) * K + k0 + kh;
      bh0 = *(const s16x8*)(Bhig + off); bh1 = *(const s16x8*)(Bhig + off + 8);
      if constexpr (SPLIT) {
        bl0 = *(const s16x8*)(Blog + off); bl1 = *(const s16x8*)(Blog + off + 8);
      }
    }
    __syncthreads();
    *(s16x8*)(sAhi + db0) = ah0; *(s16x8*)(sAhi + db1) = ah1;
    *(s16x8*)(sBhi + db0) = bh0; *(s16x8*)(sBhi + db1) = bh1;
    if constexpr (SPLIT) {
      *(s16x8*)(sAlo + db0) = al0; *(s16x8*)(sAlo + db1) = al1;
      *(s16x8*)(sBlo + db0) = bl0; *(s16x8*)(sBlo + db1) = bl1;
    }
    __syncthreads();

    s16x8 Af[4], Al[4], Bf[4], Bl[4];
    #pragma unroll
    for (int i = 0; i < 4; ++i) {
      const int off = (wr * 64 + i * 16 + fr) * 64 + ((kc * 16) ^ fsw);
      Af[i] = *(const s16x8*)(sAhi + off);
      if constexpr (SPLIT) Al[i] = *(const s16x8*)(sAlo + off);
    }
    #pragma unroll
    for (int j = 0; j < 4; ++j) {
      const int off = (wc * 64 + j * 16 + fr) * 64 + ((kc * 16) ^ fsw);
      Bf[j] = *(const s16x8*)(sBhi + off);
      if constexpr (SPLIT) Bl[j] = *(const s16x8*)(sBlo + off);
    }
    #pragma unroll
    for (int i = 0; i < 4; ++i)
      #pragma unroll
      for (int j = 0; j < 4; ++j) {
        acc[i][j] = __builtin_amdgcn_mfma_f32_16x16x32_bf16(Af[i], Bf[j], acc[i][j], 0, 0, 0);
        if constexpr (SPLIT) {
          acc[i][j] = __builtin_amdgcn_mfma_f32_16x16x32_bf16(Af[i], Bl[j], acc[i][j], 0, 0, 0);
          acc[i][j] = __builtin_amdgcn_mfma_f32_16x16x32_bf16(Al[i], Bf[j], acc[i][j], 0, 0, 0);
        }
      }
  }

  // ---- epilogue ----
  if constexpr (MODE == 2) {
    // proj: +bias, fused rotate-half RoPE for z<2 (pairs j and j+2 frags)
    #pragma unroll
    for (int i = 0; i < 4; ++i)
      #pragma unroll
      for (int j2 = 0; j2 < 2; ++j2) {
        const int col0 = n0 + wc * 64 + j2 * 16 + fr;   // col0 % 64 in [0,32)
        const int jr = col0 & 31;
        const float b0 = bias[col0], b1 = bias[col0 + 32];
        #pragma unroll
        for (int rr = 0; rr < 4; ++rr) {
          const int row = m0 + wr * 64 + i * 16 + kc * 4 + rr;
          float v0 = acc[i][j2][rr] + b0;
          float v1 = acc[i][j2 + 2][rr] + b1;
          if (z < 2) {
            const float2 cs = tab[((row & 4095) << 5) | jr];
            const float r0 = v0 * cs.x - v1 * cs.y;
            const float r1 = v1 * cs.x + v0 * cs.y;
            v0 = r0; v1 = r1;
          }
          Cf[(size_t)row * N + col0] = v0;
          Cf[(size_t)row * N + col0 + 32] = v1;
        }
      }
  } else {
    #pragma unroll
    for (int i = 0; i < 4; ++i)
      #pragma unroll
      for (int j = 0; j < 4; ++j) {
        const int col = n0 + wc * 64 + j * 16 + fr;
        #pragma unroll
        for (int rr = 0; rr < 4; ++rr) {
          const int row = m0 + wr * 64 + i * 16 + kc * 4 + rr;
          const float v = acc[i][j][rr];
          if constexpr (MODE == 0) {
            const float hv = v + bias[col];
            const unsigned short hh = f2bf(hv);
            C1[(size_t)row * N + col] = hh;
            C2[(size_t)row * N + col] = f2bf(hv - bf2f(hh));
          } else if constexpr (MODE == 1) {
            const int g = col >> 8;
            const float sg = (g == 0) ? 1.0f : ((g == 1) ? 1.41421356237309515f : 2.0f);
            const float zc = cosf(v * sg + bias[col]) * 0.08838834764831845f;
            C1[(size_t)row * N + col] = f2bf(zc);
          } else {
            Cf[(size_t)row * N + col] = v + bias[col];
          }
        }
      }
  }
}

// ======================== RoPE table ========================================
__global__ __launch_bounds__(256) void rope_table_kernel(float2* __restrict__ tab)
{
  const int idx = blockIdx.x * 256 + threadIdx.x;
  const int j = idx & 31, s = idx >> 5;
  const double inv = pow(10000.0, -(double)j * (1.0 / 32.0));
  double sd, cd;
  sincos((double)s * inv, &sd, &cd);
  tab[idx] = make_float2((float)cd, (float)sd);
}

// ======================== Nystrom RBF features ==============================
__global__ __launch_bounds__(256) void nystrom_kernel(
    const float* __restrict__ Kb, const float* __restrict__ lm,
    float* __restrict__ kny)
{
  __shared__ float lmT[64][65];
  __shared__ float lnorm[64];
  const int tid = threadIdx.x;
  for (int idx = tid; idx < 4096; idx += 256)
    lmT[idx & 63][idx >> 6] = lm[idx];
  if (tid < 64) {
    float s = 0.f;
    #pragma unroll
    for (int d = 0; d < 64; ++d) { const float v = lm[tid * 64 + d]; s = fmaf(v, v, s); }
    lnorm[tid] = s;
  }
  __syncthreads();
  const int lane = tid & 63;
  const int nw = gridDim.x * 4;
  for (int row = blockIdx.x * 4 + (tid >> 6); row < 131072; row += nw) {
    const float kd = Kb[(size_t)row * 64 + lane];
    float nk = kd * kd;
    #pragma unroll
    for (int o = 32; o > 0; o >>= 1) nk += __shfl_xor(nk, o, 64);
    float dot = 0.f;
    #pragma unroll
    for (int d = 0; d < 64; ++d) dot = fmaf(__shfl(kd, d, 64), lmT[d][lane], dot);
    kny[(size_t)row * 64 + lane] = __expf((2.f * dot - nk - lnorm[lane]) * 0.015625f);
  }
}

// ======================== FAVOR-K (MFMA) ====================================
__global__ __launch_bounds__(512) void favor_k_mfma(
    const float* __restrict__ kny,
    const unsigned short* __restrict__ oThi, const unsigned short* __restrict__ oTlo,
    const unsigned short* __restrict__ VT, float* __restrict__ KVp)
{
  const int bid = blockIdx.x;
  const int bh = bid >> 3, chunk = bid & 7;
  const int b = bh >> 4, h = bh & 15;
  const int s0 = chunk * 512;
  const int tid = threadIdx.x, lane = tid & 63, wid = tid >> 6;
  const int fr = lane & 15, kc = lane >> 4;
  const int m0w = wid * 32;

  __shared__ unsigned short P[256][40];
  __shared__ float T[8][32][84];

  s16x8 whi[2][2], wlo[2][2];
  #pragma unroll
  for (int c = 0; c < 2; ++c)
    #pragma unroll
    for (int ks = 0; ks < 2; ++ks) {
      const size_t off = (size_t)(m0w + c * 16 + fr) * 64 + ks * 32 + kc * 8;
      whi[c][ks] = *(const s16x8*)(oThi + off);
      wlo[c][ks] = *(const s16x8*)(oTlo + off);
    }

  f32x4 acc2[2][5];
  #pragma unroll
  for (int i = 0; i < 2; ++i)
    #pragma unroll
    for (int j = 0; j < 5; ++j) acc2[i][j] = f32x4{0.f, 0.f, 0.f, 0.f};

  for (int st = 0; st < 512; st += 32) {
    s16x8 ahi[2][2], alo[2][2];
    float nrm[2];
    #pragma unroll
    for (int r = 0; r < 2; ++r) {
      float part = 0.f;
      #pragma unroll
      for (int ks = 0; ks < 2; ++ks) {
        const float* ap = kny +
            ((size_t)((b * 4096 + s0 + st + r * 16 + fr) * 16 + h)) * 64 + ks * 32 + kc * 8;
        const float4 f0 = ((const float4*)ap)[0];
        const float4 f1 = ((const float4*)ap)[1];
        float v[8] = {f0.x, f0.y, f0.z, f0.w, f1.x, f1.y, f1.z, f1.w};
        #pragma unroll
        for (int u = 0; u < 8; ++u) {
          part = fmaf(v[u], v[u], part);
          const unsigned short hh = f2bf(v[u]);
          ahi[r][ks][u] = (short)hh;
          alo[r][ks][u] = (short)f2bf(v[u] - bf2f(hh));
        }
      }
      part += __shfl_xor(part, 16);
      part += __shfl_xor(part, 32);
      nrm[r] = 0.5f * part;
    }
    __syncthreads();
    #pragma unroll
    for (int r = 0; r < 2; ++r)
      #pragma unroll
      for (int c = 0; c < 2; ++c) {
        f32x4 s1 = f32x4{0.f, 0.f, 0.f, 0.f};
        #pragma unroll
        for (int ks = 0; ks < 2; ++ks) {
          s1 = __builtin_amdgcn_mfma_f32_16x16x32_bf16(alo[r][ks], whi[c][ks], s1, 0, 0, 0);
          s1 = __builtin_amdgcn_mfma_f32_16x16x32_bf16(ahi[r][ks], wlo[c][ks], s1, 0, 0, 0);
          s1 = __builtin_amdgcn_mfma_f32_16x16x32_bf16(ahi[r][ks], whi[c][ks], s1, 0, 0, 0);
        }
        #pragma unroll
        for (int reg = 0; reg < 4; ++reg) {
          const int sl = kc * 4 + reg;
          const float nn = __shfl(nrm[r], sl);
          const float p = __expf(s1[reg] - nn - 2.772588722239781f);
          P[m0w + c * 16 + fr][r * 16 + sl] = f2bf(p);
        }
      }
    __syncthreads();
    s16x8 b2[5];
    #pragma unroll
    for (int nf = 0; nf < 5; ++nf)
      b2[nf] = *(const s16x8*)(VT + ((size_t)bh * 80 + nf * 16 + fr) * 4096 +
                               s0 + st + kc * 8);
    #pragma unroll
    for (int mf = 0; mf < 2; ++mf) {
      const s16x8 a2 = *(const s16x8*)&P[m0w + mf * 16 + fr][kc * 8];
      #pragma unroll
      for (int nf = 0; nf < 5; ++nf)
        acc2[mf][nf] = __builtin_amdgcn_mfma_f32_16x16x32_bf16(a2, b2[nf], acc2[mf][nf], 0, 0, 0);
    }
  }
  #pragma unroll
  for (int mf = 0; mf < 2; ++mf)
    #pragma unroll
    for (int nf = 0; nf < 5; ++nf)
      #pragma unroll
      for (int reg = 0; reg < 4; ++reg)
        T[wid][mf * 16 + kc * 4 + reg][nf * 16 + fr] = acc2[mf][nf][reg];
  __syncthreads();
  #pragma unroll
  for (int i = 0; i < 40; ++i) {
    const int flat = i * 64 + lane;
    const int n = flat >> 5, ml = flat & 31;
    KVp[((size_t)bid * 80 + n) * 256 + m0w + ml] = T[wid][ml][n];
  }
}

// ======================== reduce KVp -> KVXT bf16 ===========================
__global__ __launch_bounds__(256) void reduce_kvxt_kernel(
    const float* __restrict__ KVp, unsigned short* __restrict__ KVXT)
{
  const int bh = blockIdx.x;
  const int m = threadIdx.x;
  for (int n = 0; n < 80; ++n) {
    float s = 0.f;
    #pragma unroll
    for (int c = 0; c < 8; ++c)
      s += KVp[((size_t)(bh * 8 + c) * 80 + n) * 256 + m];
    KVXT[((size_t)bh * 80 + n) * 256 + m] = f2bf(s);
  }
}

// ======================== FAVOR-Q (MFMA) ====================================
__global__ __launch_bounds__(512) void favor_q_mfma(
    const float* __restrict__ Q,
    const unsigned short* __restrict__ oThi, const unsigned short* __restrict__ oTlo,
    const unsigned short* __restrict__ KVXT, unsigned short* __restrict__ O)
{
  const int bid = blockIdx.x;
  const int bh = bid >> 4, chunk = bid & 15;
  const int b = bh >> 4, h = bh & 15;
  const int s0 = chunk * 256;
  const int tid = threadIdx.x, lane = tid & 63, wid = tid >> 6;
  const int fr = lane & 15, kc = lane >> 4;
  const int ws0 = s0 + wid * 32;

  __shared__ unsigned short KX[80][264];
  __shared__ unsigned short P[8][32][66];

  for (int i = tid; i < 80 * 256; i += 512)
    KX[i >> 8][i & 255] = KVXT[(size_t)bh * 80 * 256 + i];
  __syncthreads();

  s16x8 ahi[2][2], alo[2][2];
  float nrm[2];
  #pragma unroll
  for (int r = 0; r < 2; ++r) {
    float part = 0.f;
    #pragma unroll
    for (int ks = 0; ks < 2; ++ks) {
      const float* ap = Q + ((size_t)(b * 4096 + ws0 + r * 16 + fr)) * 1024 +
                        h * 64 + ks * 32 + kc * 8;
      const float4 f0 = ((const float4*)ap)[0];
      const float4 f1 = ((const float4*)ap)[1];
      float v[8] = {f0.x, f0.y, f0.z, f0.w, f1.x, f1.y, f1.z, f1.w};
      #pragma unroll
      for (int u = 0; u < 8; ++u) {
        part = fmaf(v[u], v[u], part);
        const unsigned short hh = f2bf(v[u]);
        ahi[r][ks][u] = (short)hh;
        alo[r][ks][u] = (short)f2bf(v[u] - bf2f(hh));
      }
    }
    part += __shfl_xor(part, 16);
    part += __shfl_xor(part, 32);
    nrm[r] = 0.5f * part;
  }

  f32x4 acc2[2][5];
  #pragma unroll
  for (int i = 0; i < 2; ++i)
    #pragma unroll
    for (int j = 0; j < 5; ++j) acc2[i][j] = f32x4{0.f, 0.f, 0.f, 0.f};

  for (int mc = 0; mc < 4; ++mc) {
    __syncthreads();
    #pragma unroll
    for (int r = 0; r < 2; ++r)
      #pragma unroll
      for (int c = 0; c < 4; ++c) {
        f32x4 s1 = f32x4{0.f, 0.f, 0.f, 0.f};
        #pragma unroll
        for (int ks = 0; ks < 2; ++ks) {
          const size_t off = (size_t)(mc * 64 + c * 16 + fr) * 64 + ks * 32 + kc * 8;
          const s16x8 bh1 = *(const s16x8*)(oThi + off);
          const s16x8 bl1 = *(const s16x8*)(oTlo + off);
          s1 = __builtin_amdgcn_mfma_f32_16x16x32_bf16(alo[r][ks], bh1, s1, 0, 0, 0);
          s1 = __builtin_amdgcn_mfma_f32_16x16x32_bf16(ahi[r][ks], bl1, s1, 0, 0, 0);
          s1 = __builtin_amdgcn_mfma_f32_16x16x32_bf16(ahi[r][ks], bh1, s1, 0, 0, 0);
        }
        #pragma unroll
        for (int reg = 0; reg < 4; ++reg) {
          const int sl = kc * 4 + reg;
          const float nn = __shfl(nrm[r], sl);
          const float p = __expf(s1[reg] - nn - 2.772588722239781f);
          P[wid][r * 16 + sl][c * 16 + fr] = f2bf(p);
        }
      }
    __syncthreads();
    #pragma unroll
    for (int ks2 = 0; ks2 < 2; ++ks2) {
      s16x8 b2[5];
      #pragma unroll
      for (int nf = 0; nf < 5; ++nf)
        b2[nf] = *(const s16x8*)&KX[nf * 16 + fr][mc * 64 + ks2 * 32 + kc * 8];
      #pragma unroll
      for (int r = 0; r < 2; ++r) {
        const s16x8 a2 = *(const s16x8*)&P[wid][r * 16 + fr][ks2 * 32 + kc * 8];
        #pragma unroll
        for (int nf = 0; nf < 5; ++nf)
          acc2[r][nf] = __builtin_amdgcn_mfma_f32_16x16x32_bf16(a2, b2[nf], acc2[r][nf], 0, 0, 0);
      }
    }
  }
  #pragma unroll
  for (int r = 0; r < 2; ++r)
    #pragma unroll
    for (int reg = 0; reg < 4; ++reg) {
      const int s = ws0 + r * 16 + kc * 4 + reg;
      const float dv = __shfl(acc2[r][4][reg], lane & 48) + 1e-6f;
      #pragma unroll
      for (int nf = 0; nf < 4; ++nf)
        O[(size_t)(b * 4096 + s) * 1024 + h * 64 + nf * 16 + fr] =
            f2bf(acc2[r][nf][reg] / dv);
    }
}

// ======================== launcher ==========================================
extern "C" void kernel_launch(void* const* d_in, const int* in_sizes, int n_in,
                              void* d_out, int out_size, void* d_ws, size_t ws_size,
                              hipStream_t stream)
{
  const float* x      = (const float*)d_in[0];
  const float* conv_k = (const float*)d_in[1];
  const float* conv_b = (const float*)d_in[2];
  const float* rff_w  = (const float*)d_in[3];
  const float* rff_b  = (const float*)d_in[4];
  const float* proj_w = (const float*)d_in[5];
  const float* proj_b = (const float*)d_in[6];
  const float* omega  = (const float*)d_in[7];
  const float* lm     = (const float*)d_in[8];
  const float* out_w  = (const float*)d_in[9];
  const float* out_b  = (const float*)d_in[10];

  char* wsb = (char*)d_ws;
  size_t o = 0;
  auto alloc = [&](size_t bytes) {
    char* p = wsb + o;
    o = (o + bytes + 255) & ~(size_t)255;
    return p;
  };
  // --- region A: persistent (weights/tables), ~27 MB
  unsigned short* Wc_hi = (unsigned short*)alloc(4718592);
  unsigned short* Wc_lo = (unsigned short*)alloc(4718592);
  unsigned short* Wr_hi = (unsigned short*)alloc(4718592);
  unsigned short* Wr_lo = (unsigned short*)alloc(4718592);
  unsigned short* Wp    = (unsigned short*)alloc(4718592);
  unsigned short* Wo    = (unsigned short*)alloc(2097152);
  unsigned short* oThi  = (unsigned short*)alloc(32768);
  unsigned short* oTlo  = (unsigned short*)alloc(32768);
  float2* tab           = (float2*)alloc(1048576);
  // --- region B (40 MB): xhi/xlo -> feats -> {VT, Obf, KVXT}
  char* RB = alloc(41943040);
  unsigned short* xhi   = (unsigned short*)RB;                  // 16,777,216
  unsigned short* xlo   = (unsigned short*)(RB + 16777216);     // 16,777,216
  unsigned short* feats = (unsigned short*)RB;                  // 37,748,736 (3x)
  unsigned short* VT    = (unsigned short*)RB;                  // 20,971,520
  unsigned short* Obf   = (unsigned short*)(RB + 20971520);     // 16,777,216
  unsigned short* KVXT  = (unsigned short*)(RB + 37748736);     //  1,310,720
  // --- region C (96 MB): h hi/lo (3x) -> QKV f32 (3x)
  char* RC = alloc(100663296);
  unsigned short* hhi   = (unsigned short*)RC;                  // 50,331,648 (3x)
  unsigned short* hlo   = (unsigned short*)(RC + 50331648);     // 50,331,648 (3x)
  float* QKV            = (float*)RC;                           // 100,663,296 (3x)
  // --- region E: kny + KVp
  float* kny = (float*)alloc(33554432);
  float* KVp = (float*)alloc(20971520);

  dim3 blk(256);
  // prep
  split_prep_kernel<<<4096, blk, 0, stream>>>(x, xhi, xlo, 1048576);
  wconv_kernel<0><<<dim3(12, 16, 3), blk, 0, stream>>>(conv_k, Wc_hi, Wc_lo);
  wconv_kernel<1><<<dim3(16, 4, 9),  blk, 0, stream>>>(rff_w, Wr_hi, Wr_lo);
  wconv_kernel<2><<<dim3(12, 16, 3), blk, 0, stream>>>(proj_w, Wp, nullptr);
  wconv_kernel<3><<<dim3(16, 16, 1), blk, 0, stream>>>(out_w, Wo, nullptr);
  omega_prep_kernel<<<64, blk, 0, stream>>>(omega, oThi, oTlo);
  rope_table_kernel<<<512, blk, 0, stream>>>(tab);

  // z-batched QKV chain: conv -> rff -> proj(+rope)
  gemm_mfma<0><<<dim3(8, 64, 3), blk, 0, stream>>>(
      xhi, xlo, Wc_hi, Wc_lo, conv_b, nullptr,
      nullptr, hhi, hlo, 8192, 1024, 768);
  gemm_mfma<1><<<dim3(6, 64, 3), blk, 0, stream>>>(
      hhi, hlo, Wr_hi, Wr_lo, rff_b, nullptr,
      nullptr, feats, nullptr, 8192, 768, 1024);
  gemm_mfma<2><<<dim3(8, 64, 3), blk, 0, stream>>>(
      feats, nullptr, Wp, nullptr, proj_b, tab,
      QKV, nullptr, nullptr, 8192, 1024, 768);

  float* Qb = QKV;
  float* Kb = QKV + 8388608;
  float* Vb = QKV + 16777216;
  vt_kernel<<<dim3(32, 64), blk, 0, stream>>>(Vb, VT);
  nystrom_kernel<<<512, blk, 0, stream>>>(Kb, lm, kny);
  favor_k_mfma<<<256, dim3(512), 0, stream>>>(kny, oThi, oTlo, VT, KVp);
  reduce_kvxt_kernel<<<32, blk, 0, stream>>>(KVp, KVXT);
  favor_q_mfma<<<512, dim3(512), 0, stream>>>(Qb, oThi, oTlo, KVXT, Obf);
  gemm_mfma<3><<<dim3(8, 64), blk, 0, stream>>>(
      Obf, nullptr, Wo, nullptr, out_b, nullptr,
      (float*)d_out, nullptr, nullptr, 8192, 1024, 1024);
}

// Round 8
// 1141.762 us; speedup vs baseline: 1.0757x; 1.0183x over previous
//
#include <hip/hip_runtime.h>
#include <math.h>

// ---------------------------------------------------------------------------
// B=2, S=4096, C=1024, H=16, Dh=64, G=3, Ms=256, NRF=256, L=64
// Round 8: GEMM staging via global_load_lds width-16 (m97 structure):
// per-lane pre-swizzled global source -> linear LDS DMA reproduces the
// existing XOR-swizzled layout; read path unchanged from R7.
// ---------------------------------------------------------------------------

using f32x4 = __attribute__((ext_vector_type(4))) float;
using s16x8 = __attribute__((ext_vector_type(8))) short;

__device__ __forceinline__ unsigned short f2bf(float x) {
  unsigned u = __float_as_uint(x);
  unsigned r = u + 0x7fffu + ((u >> 16) & 1u);
  return (unsigned short)(r >> 16);
}
__device__ __forceinline__ float bf2f(unsigned short h) {
  return __uint_as_float(((unsigned)h) << 16);
}

// async global -> LDS, 16B per lane; lds dst is wave-uniform base + lane*16
__device__ __forceinline__ void gload16(const void* g, void* l) {
  __builtin_amdgcn_global_load_lds(
      (const __attribute__((address_space(1))) void*)g,
      (__attribute__((address_space(3))) void*)l, 16, 0, 0);
}

// ======================== f32 -> bf16 hi/lo splitter ========================
__global__ __launch_bounds__(256) void split_prep_kernel(
    const float* __restrict__ in, unsigned short* __restrict__ ohi,
    unsigned short* __restrict__ olo, int n8)
{
  const int i = blockIdx.x * 256 + threadIdx.x;
  if (i >= n8) return;
  const float4 f0 = ((const float4*)in)[i * 2];
  const float4 f1 = ((const float4*)in)[i * 2 + 1];
  const float v[8] = {f0.x, f0.y, f0.z, f0.w, f1.x, f1.y, f1.z, f1.w};
  s16x8 hi, lo;
  #pragma unroll
  for (int u = 0; u < 8; ++u) {
    const unsigned short hh = f2bf(v[u]);
    hi[u] = (short)hh;
    lo[u] = (short)f2bf(v[u] - bf2f(hh));
  }
  ((s16x8*)ohi)[i] = hi;
  ((s16x8*)olo)[i] = lo;
}

// ======================== weight transpose + convert ========================
template<int WM>  // 0 conv(3i, split) 1 rff(9 z=i*3+g, split) 2 proj(3i) 3 out_w
__global__ __launch_bounds__(256) void wconv_kernel(
    const float* __restrict__ in0, unsigned short* __restrict__ ohi,
    unsigned short* __restrict__ olo)
{
  int K, N;
  const float* in;
  unsigned short *oh, *ol = nullptr;
  const int z = blockIdx.z;
  if constexpr (WM == 0) {
    K = 768; N = 1024;
    in = in0 + (size_t)z * 786432;
    oh = ohi + (size_t)z * 786432; ol = olo + (size_t)z * 786432;
  } else if constexpr (WM == 1) {
    K = 1024; N = 256;
    const int i = z / 3, g = z % 3;
    in = in0 + (size_t)i * 786432 + (size_t)g * 262144;
    oh = ohi + (size_t)i * 786432 + (size_t)g * 262144;
    ol = olo + (size_t)i * 786432 + (size_t)g * 262144;
  } else if constexpr (WM == 2) {
    K = 768; N = 1024;
    in = in0 + (size_t)z * 786432; oh = ohi + (size_t)z * 786432;
  } else {
    K = 1024; N = 1024; in = in0; oh = ohi;
  }
  const int k0 = blockIdx.x * 64, n0 = blockIdx.y * 64;
  __shared__ float t[64][65];
  const int tid = threadIdx.x, tn = tid & 63, tr = tid >> 6;
  #pragma unroll 4
  for (int p = 0; p < 16; ++p) {
    const int kk = p * 4 + tr;
    t[kk][tn] = in[(size_t)(k0 + kk) * N + n0 + tn];
  }
  __syncthreads();
  #pragma unroll 4
  for (int p = 0; p < 16; ++p) {
    const int nn = p * 4 + tr;
    const float v = t[tn][nn];
    const unsigned short hi = f2bf(v);
    oh[(size_t)(n0 + nn) * K + k0 + tn] = hi;
    if constexpr (WM <= 1)
      ol[(size_t)(n0 + nn) * K + k0 + tn] = f2bf(v - bf2f(hi));
  }
}

// omega [64][256] f32 -> omegaT [256][64] bf16 hi/lo
__global__ __launch_bounds__(256) void omega_prep_kernel(
    const float* __restrict__ omega, unsigned short* __restrict__ oThi,
    unsigned short* __restrict__ oTlo)
{
  const int idx = blockIdx.x * 256 + threadIdx.x;  // 16384
  const int m = idx >> 6, d = idx & 63;
  const float v = omega[d * 256 + m];
  const unsigned short hi = f2bf(v);
  oThi[idx] = hi;
  oTlo[idx] = f2bf(v - bf2f(hi));
}

// V [8192][1024] f32 -> VT[bh][80][4096] bf16; rows 64..79: ksum row + zeros
__global__ __launch_bounds__(256) void vt_kernel(
    const float* __restrict__ V, unsigned short* __restrict__ VT)
{
  const int bh = blockIdx.x, sb = blockIdx.y;
  const int b = bh >> 4, h = bh & 15;
  __shared__ float t[64][65];
  const int tid = threadIdx.x, tn = tid & 63, tr = tid >> 6;
  #pragma unroll 4
  for (int p = 0; p < 16; ++p)
    t[p * 4 + tr][tn] =
        V[(size_t)(b * 4096 + sb * 64 + p * 4 + tr) * 1024 + h * 64 + tn];
  __syncthreads();
  #pragma unroll 4
  for (int p = 0; p < 16; ++p)
    VT[((size_t)bh * 80 + p * 4 + tr) * 4096 + sb * 64 + tn] =
        f2bf(t[tn][p * 4 + tr]);
  #pragma unroll
  for (int p = 0; p < 4; ++p) {
    const int rr = p * 4 + tr;
    VT[((size_t)bh * 80 + 64 + rr) * 4096 + sb * 64 + tn] =
        (rr == 0) ? 0x3F80 : 0;
  }
}

// ======================== MFMA GEMM (global_load_lds staging) ===============
// 128x128 tile, BK=32, 256 threads (2x2 waves), 16x16x32 bf16 MFMA.
// LDS tile layout (per buffer, 8KB): row r (0..127) at bytes r*64; chunk c
// (16B, c=0..3 covering k=c*8..c*8+8 bf16) stored at (c*16)^(((r>>1)&3)<<4).
// DMA writes linearly (seg*1024 + lane*16); source address pre-permuted so
// content matches that layout. Read path identical to R7 (0 bank conflicts).
template<int MODE>
__global__ __launch_bounds__(256, MODE >= 2 ? 4 : 3) void gemm_mfma(
    const unsigned short* __restrict__ Ahi, const unsigned short* __restrict__ Alo,
    const unsigned short* __restrict__ Bhig, const unsigned short* __restrict__ Blog,
    const float* __restrict__ bias, const float2* __restrict__ tab,
    float* __restrict__ Cf, unsigned short* __restrict__ C1,
    unsigned short* __restrict__ C2,
    int M, int N, int K)
{
  constexpr bool SPLIT = (MODE <= 1);
  __shared__ alignas(16) char smem[SPLIT ? 32768 : 16384];
  char* const sAhi = smem;
  char* const sBhi = smem + (SPLIT ? 16384 : 8192);
  char* const sAlo = smem + 8192;
  char* const sBlo = smem + 24576;

  const int z = (MODE <= 2) ? blockIdx.z : 0;
  if constexpr (MODE == 0) {
    Bhig += (size_t)z * 786432; Blog += (size_t)z * 786432;
    bias += z * 1024;
    C1 += (size_t)z * 8388608; C2 += (size_t)z * 8388608;
  } else if constexpr (MODE == 1) {
    Ahi += (size_t)z * 8388608; Alo += (size_t)z * 8388608;
    Bhig += (size_t)z * 786432; Blog += (size_t)z * 786432;
    bias += z * 768;
    C1 += (size_t)z * 6291456;
  } else if constexpr (MODE == 2) {
    Ahi += (size_t)z * 6291456;
    Bhig += (size_t)z * 786432;
    bias += z * 1024;
    Cf += (size_t)z * 8388608;
  }

  const int tid = threadIdx.x;
  const int n0 = blockIdx.x * 128;
  const int m0 = blockIdx.y * 128;

  const int lane = tid & 63, wid = tid >> 6;
  const int wr = wid >> 1, wc = wid & 1;
  const int fr = lane & 15, kc = lane >> 4;
  const int fsw = ((fr >> 1) & 3) << 4;

  // DMA staging geometry: wave wid owns 1KB segments {2*wid, 2*wid+1} of each
  // buffer. Lane covers row rX = seg*16 + (lane>>2), chunk slot lane&3; the
  // chunk INDEX that belongs at that slot is (lane&3) ^ ((row>>1)&3).
  const int seg0 = wid * 2;
  const int r0 = seg0 * 16 + (lane >> 2);
  const int r1 = r0 + 16;
  const int cp = lane & 3;
  const int c0e = (cp ^ ((r0 >> 1) & 3)) * 8;   // element (short) offset in k
  const int c1e = (cp ^ ((r1 >> 1) & 3)) * 8;
  char* const dA0 = sAhi + seg0 * 1024;  char* const dA1 = dA0 + 1024;
  char* const dL0 = sAlo + seg0 * 1024;  char* const dL1 = dL0 + 1024;
  char* const dB0 = sBhi + seg0 * 1024;  char* const dB1 = dB0 + 1024;
  char* const dBl0 = sBlo + seg0 * 1024; char* const dBl1 = dBl0 + 1024;

  f32x4 acc[4][4];
  #pragma unroll
  for (int i = 0; i < 4; ++i)
    #pragma unroll
    for (int j = 0; j < 4; ++j) acc[i][j] = f32x4{0.f, 0.f, 0.f, 0.f};

  for (int k0 = 0; k0 < K; k0 += 32) {
    __syncthreads();   // WAR: prior tile's ds_reads complete before DMA lands
    // ---- issue staging DMAs ----
    if constexpr (MODE == 0) {
      const int t = k0 >> 8;
      const int cb = (n0 >> 8) * 256 + (k0 & 255);
      const int g0 = m0 + r0, g1 = m0 + r1;
      int s0 = (g0 & 4095) + t - 1; s0 = s0 < 0 ? 0 : (s0 > 4095 ? 4095 : s0);
      int s1 = (g1 & 4095) + t - 1; s1 = s1 < 0 ? 0 : (s1 > 4095 ? 4095 : s1);
      const size_t o0 = ((size_t)((g0 >> 12) * 4096 + s0)) * 1024 + cb;
      const size_t o1 = ((size_t)((g1 >> 12) * 4096 + s1)) * 1024 + cb;
      gload16(Ahi + o0 + c0e, dA0);
      gload16(Ahi + o1 + c1e, dA1);
      gload16(Alo + o0 + c0e, dL0);
      gload16(Alo + o1 + c1e, dL1);
    } else {
      const size_t o0 = (size_t)(m0 + r0) * K + k0;
      const size_t o1 = (size_t)(m0 + r1) * K + k0;
      gload16(Ahi + o0 + c0e, dA0);
      gload16(Ahi + o1 + c1e, dA1);
      if constexpr (SPLIT) {
        gload16(Alo + o0 + c0e, dL0);
        gload16(Alo + o1 + c1e, dL1);
      }
    }
    {
      const size_t o0 = (size_t)(n0 + r0) * K + k0;
      const size_t o1 = (size_t)(n0 + r1) * K + k0;
      gload16(Bhig + o0 + c0e, dB0);
      gload16(Bhig + o1 + c1e, dB1);
      if constexpr (SPLIT) {
        gload16(Blog + o0 + c0e, dBl0);
        gload16(Blog + o1 + c1e, dBl1);
      }
    }
    __syncthreads();   // drains vmcnt(0): tile staged

    // ---- conv boundary rows: zero the single invalid row (rare blocks) ----
    if constexpr (MODE == 0) {
      const int t = k0 >> 8;
      int zr = -1;
      if (t == 0 && (m0 & 4095) == 0) zr = 0;
      if (t == 2 && (m0 & 4095) == 3968) zr = 127;
      if (zr >= 0) {
        if (tid < 8) {
          char* buf = (tid < 4) ? sAhi : sAlo;
          *(s16x8*)(buf + zr * 64 + (tid & 3) * 16) = s16x8{0,0,0,0,0,0,0,0};
        }
        __syncthreads();
      }
    }

    // ---- fragments + MFMA (unchanged) ----
    s16x8 Af[4], Al[4], Bf[4], Bl[4];
    #pragma unroll
    for (int i = 0; i < 4; ++i) {
      const int off = (wr * 64 + i * 16 + fr) * 64 + ((kc * 16) ^ fsw);
      Af[i] = *(const s16x8*)(sAhi + off);
      if constexpr (SPLIT) Al[i] = *(const s16x8*)(sAlo + off);
    }
    #pragma unroll
    for (int j = 0; j < 4; ++j) {
      const int off = (wc * 64 + j * 16 + fr) * 64 + ((kc * 16) ^ fsw);
      Bf[j] = *(const s16x8*)(sBhi + off);
      if constexpr (SPLIT) Bl[j] = *(const s16x8*)(sBlo + off);
    }
    #pragma unroll
    for (int i = 0; i < 4; ++i)
      #pragma unroll
      for (int j = 0; j < 4; ++j) {
        acc[i][j] = __builtin_amdgcn_mfma_f32_16x16x32_bf16(Af[i], Bf[j], acc[i][j], 0, 0, 0);
        if constexpr (SPLIT) {
          acc[i][j] = __builtin_amdgcn_mfma_f32_16x16x32_bf16(Af[i], Bl[j], acc[i][j], 0, 0, 0);
          acc[i][j] = __builtin_amdgcn_mfma_f32_16x16x32_bf16(Al[i], Bf[j], acc[i][j], 0, 0, 0);
        }
      }
  }

  // ---- epilogue (unchanged from R7) ----
  if constexpr (MODE == 2) {
    #pragma unroll
    for (int i = 0; i < 4; ++i)
      #pragma unroll
      for (int j2 = 0; j2 < 2; ++j2) {
        const int col0 = n0 + wc * 64 + j2 * 16 + fr;
        const int jr = col0 & 31;
        const float b0 = bias[col0], b1 = bias[col0 + 32];
        #pragma unroll
        for (int rr = 0; rr < 4; ++rr) {
          const int row = m0 + wr * 64 + i * 16 + kc * 4 + rr;
          float v0 = acc[i][j2][rr] + b0;
          float v1 = acc[i][j2 + 2][rr] + b1;
          if (z < 2) {
            const float2 cs = tab[((row & 4095) << 5) | jr];
            const float rr0 = v0 * cs.x - v1 * cs.y;
            const float rr1 = v1 * cs.x + v0 * cs.y;
            v0 = rr0; v1 = rr1;
          }
          Cf[(size_t)row * N + col0] = v0;
          Cf[(size_t)row * N + col0 + 32] = v1;
        }
      }
  } else {
    #pragma unroll
    for (int i = 0; i < 4; ++i)
      #pragma unroll
      for (int j = 0; j < 4; ++j) {
        const int col = n0 + wc * 64 + j * 16 + fr;
        #pragma unroll
        for (int rr = 0; rr < 4; ++rr) {
          const int row = m0 + wr * 64 + i * 16 + kc * 4 + rr;
          const float v = acc[i][j][rr];
          if constexpr (MODE == 0) {
            const float hv = v + bias[col];
            const unsigned short hh = f2bf(hv);
            C1[(size_t)row * N + col] = hh;
            C2[(size_t)row * N + col] = f2bf(hv - bf2f(hh));
          } else if constexpr (MODE == 1) {
            const int g = col >> 8;
            const float sg = (g == 0) ? 1.0f : ((g == 1) ? 1.41421356237309515f : 2.0f);
            const float zc = cosf(v * sg + bias[col]) * 0.08838834764831845f;
            C1[(size_t)row * N + col] = f2bf(zc);
          } else {
            Cf[(size_t)row * N + col] = v + bias[col];
          }
        }
      }
  }
}

// ======================== RoPE table ========================================
__global__ __launch_bounds__(256) void rope_table_kernel(float2* __restrict__ tab)
{
  const int idx = blockIdx.x * 256 + threadIdx.x;
  const int j = idx & 31, s = idx >> 5;
  const double inv = pow(10000.0, -(double)j * (1.0 / 32.0));
  double sd, cd;
  sincos((double)s * inv, &sd, &cd);
  tab[idx] = make_float2((float)cd, (float)sd);
}

// ======================== Nystrom RBF features ==============================
__global__ __launch_bounds__(256) void nystrom_kernel(
    const float* __restrict__ Kb, const float* __restrict__ lm,
    float* __restrict__ kny)
{
  __shared__ float lmT[64][65];
  __shared__ float lnorm[64];
  const int tid = threadIdx.x;
  for (int idx = tid; idx < 4096; idx += 256)
    lmT[idx & 63][idx >> 6] = lm[idx];
  if (tid < 64) {
    float s = 0.f;
    #pragma unroll
    for (int d = 0; d < 64; ++d) { const float v = lm[tid * 64 + d]; s = fmaf(v, v, s); }
    lnorm[tid] = s;
  }
  __syncthreads();
  const int lane = tid & 63;
  const int nw = gridDim.x * 4;
  for (int row = blockIdx.x * 4 + (tid >> 6); row < 131072; row += nw) {
    const float kd = Kb[(size_t)row * 64 + lane];
    float nk = kd * kd;
    #pragma unroll
    for (int o = 32; o > 0; o >>= 1) nk += __shfl_xor(nk, o, 64);
    float dot = 0.f;
    #pragma unroll
    for (int d = 0; d < 64; ++d) dot = fmaf(__shfl(kd, d, 64), lmT[d][lane], dot);
    kny[(size_t)row * 64 + lane] = __expf((2.f * dot - nk - lnorm[lane]) * 0.015625f);
  }
}

// ======================== FAVOR-K (MFMA) ====================================
__global__ __launch_bounds__(512) void favor_k_mfma(
    const float* __restrict__ kny,
    const unsigned short* __restrict__ oThi, const unsigned short* __restrict__ oTlo,
    const unsigned short* __restrict__ VT, float* __restrict__ KVp)
{
  const int bid = blockIdx.x;
  const int bh = bid >> 3, chunk = bid & 7;
  const int b = bh >> 4, h = bh & 15;
  const int s0 = chunk * 512;
  const int tid = threadIdx.x, lane = tid & 63, wid = tid >> 6;
  const int fr = lane & 15, kc = lane >> 4;
  const int m0w = wid * 32;

  __shared__ unsigned short P[256][40];
  __shared__ float T[8][32][84];

  s16x8 whi[2][2], wlo[2][2];
  #pragma unroll
  for (int c = 0; c < 2; ++c)
    #pragma unroll
    for (int ks = 0; ks < 2; ++ks) {
      const size_t off = (size_t)(m0w + c * 16 + fr) * 64 + ks * 32 + kc * 8;
      whi[c][ks] = *(const s16x8*)(oThi + off);
      wlo[c][ks] = *(const s16x8*)(oTlo + off);
    }

  f32x4 acc2[2][5];
  #pragma unroll
  for (int i = 0; i < 2; ++i)
    #pragma unroll
    for (int j = 0; j < 5; ++j) acc2[i][j] = f32x4{0.f, 0.f, 0.f, 0.f};

  for (int st = 0; st < 512; st += 32) {
    s16x8 ahi[2][2], alo[2][2];
    float nrm[2];
    #pragma unroll
    for (int r = 0; r < 2; ++r) {
      float part = 0.f;
      #pragma unroll
      for (int ks = 0; ks < 2; ++ks) {
        const float* ap = kny +
            ((size_t)((b * 4096 + s0 + st + r * 16 + fr) * 16 + h)) * 64 + ks * 32 + kc * 8;
        const float4 f0 = ((const float4*)ap)[0];
        const float4 f1 = ((const float4*)ap)[1];
        float v[8] = {f0.x, f0.y, f0.z, f0.w, f1.x, f1.y, f1.z, f1.w};
        #pragma unroll
        for (int u = 0; u < 8; ++u) {
          part = fmaf(v[u], v[u], part);
          const unsigned short hh = f2bf(v[u]);
          ahi[r][ks][u] = (short)hh;
          alo[r][ks][u] = (short)f2bf(v[u] - bf2f(hh));
        }
      }
      part += __shfl_xor(part, 16);
      part += __shfl_xor(part, 32);
      nrm[r] = 0.5f * part;
    }
    __syncthreads();
    #pragma unroll
    for (int r = 0; r < 2; ++r)
      #pragma unroll
      for (int c = 0; c < 2; ++c) {
        f32x4 s1 = f32x4{0.f, 0.f, 0.f, 0.f};
        #pragma unroll
        for (int ks = 0; ks < 2; ++ks) {
          s1 = __builtin_amdgcn_mfma_f32_16x16x32_bf16(alo[r][ks], whi[c][ks], s1, 0, 0, 0);
          s1 = __builtin_amdgcn_mfma_f32_16x16x32_bf16(ahi[r][ks], wlo[c][ks], s1, 0, 0, 0);
          s1 = __builtin_amdgcn_mfma_f32_16x16x32_bf16(ahi[r][ks], whi[c][ks], s1, 0, 0, 0);
        }
        #pragma unroll
        for (int reg = 0; reg < 4; ++reg) {
          const int sl = kc * 4 + reg;
          const float nn = __shfl(nrm[r], sl);
          const float p = __expf(s1[reg] - nn - 2.772588722239781f);
          P[m0w + c * 16 + fr][r * 16 + sl] = f2bf(p);
        }
      }
    __syncthreads();
    s16x8 b2[5];
    #pragma unroll
    for (int nf = 0; nf < 5; ++nf)
      b2[nf] = *(const s16x8*)(VT + ((size_t)bh * 80 + nf * 16 + fr) * 4096 +
                               s0 + st + kc * 8);
    #pragma unroll
    for (int mf = 0; mf < 2; ++mf) {
      const s16x8 a2 = *(const s16x8*)&P[m0w + mf * 16 + fr][kc * 8];
      #pragma unroll
      for (int nf = 0; nf < 5; ++nf)
        acc2[mf][nf] = __builtin_amdgcn_mfma_f32_16x16x32_bf16(a2, b2[nf], acc2[mf][nf], 0, 0, 0);
    }
  }
  #pragma unroll
  for (int mf = 0; mf < 2; ++mf)
    #pragma unroll
    for (int nf = 0; nf < 5; ++nf)
      #pragma unroll
      for (int reg = 0; reg < 4; ++reg)
        T[wid][mf * 16 + kc * 4 + reg][nf * 16 + fr] = acc2[mf][nf][reg];
  __syncthreads();
  #pragma unroll
  for (int i = 0; i < 40; ++i) {
    const int flat = i * 64 + lane;
    const int n = flat >> 5, ml = flat & 31;
    KVp[((size_t)bid * 80 + n) * 256 + m0w + ml] = T[wid][ml][n];
  }
}

// ======================== reduce KVp -> KVXT bf16 ===========================
__global__ __launch_bounds__(256) void reduce_kvxt_kernel(
    const float* __restrict__ KVp, unsigned short* __restrict__ KVXT)
{
  const int bh = blockIdx.x;
  const int m = threadIdx.x;
  for (int n = 0; n < 80; ++n) {
    float s = 0.f;
    #pragma unroll
    for (int c = 0; c < 8; ++c)
      s += KVp[((size_t)(bh * 8 + c) * 80 + n) * 256 + m];
    KVXT[((size_t)bh * 80 + n) * 256 + m] = f2bf(s);
  }
}

// ======================== FAVOR-Q (MFMA) ====================================
__global__ __launch_bounds__(512) void favor_q_mfma(
    const float* __restrict__ Q,
    const unsigned short* __restrict__ oThi, const unsigned short* __restrict__ oTlo,
    const unsigned short* __restrict__ KVXT, unsigned short* __restrict__ O)
{
  const int bid = blockIdx.x;
  const int bh = bid >> 4, chunk = bid & 15;
  const int b = bh >> 4, h = bh & 15;
  const int s0 = chunk * 256;
  const int tid = threadIdx.x, lane = tid & 63, wid = tid >> 6;
  const int fr = lane & 15, kc = lane >> 4;
  const int ws0 = s0 + wid * 32;

  __shared__ unsigned short KX[80][264];
  __shared__ unsigned short P[8][32][66];

  for (int i = tid; i < 80 * 256; i += 512)
    KX[i >> 8][i & 255] = KVXT[(size_t)bh * 80 * 256 + i];
  __syncthreads();

  s16x8 ahi[2][2], alo[2][2];
  float nrm[2];
  #pragma unroll
  for (int r = 0; r < 2; ++r) {
    float part = 0.f;
    #pragma unroll
    for (int ks = 0; ks < 2; ++ks) {
      const float* ap = Q + ((size_t)(b * 4096 + ws0 + r * 16 + fr)) * 1024 +
                        h * 64 + ks * 32 + kc * 8;
      const float4 f0 = ((const float4*)ap)[0];
      const float4 f1 = ((const float4*)ap)[1];
      float v[8] = {f0.x, f0.y, f0.z, f0.w, f1.x, f1.y, f1.z, f1.w};
      #pragma unroll
      for (int u = 0; u < 8; ++u) {
        part = fmaf(v[u], v[u], part);
        const unsigned short hh = f2bf(v[u]);
        ahi[r][ks][u] = (short)hh;
        alo[r][ks][u] = (short)f2bf(v[u] - bf2f(hh));
      }
    }
    part += __shfl_xor(part, 16);
    part += __shfl_xor(part, 32);
    nrm[r] = 0.5f * part;
  }

  f32x4 acc2[2][5];
  #pragma unroll
  for (int i = 0; i < 2; ++i)
    #pragma unroll
    for (int j = 0; j < 5; ++j) acc2[i][j] = f32x4{0.f, 0.f, 0.f, 0.f};

  for (int mc = 0; mc < 4; ++mc) {
    __syncthreads();
    #pragma unroll
    for (int r = 0; r < 2; ++r)
      #pragma unroll
      for (int c = 0; c < 4; ++c) {
        f32x4 s1 = f32x4{0.f, 0.f, 0.f, 0.f};
        #pragma unroll
        for (int ks = 0; ks < 2; ++ks) {
          const size_t off = (size_t)(mc * 64 + c * 16 + fr) * 64 + ks * 32 + kc * 8;
          const s16x8 bh1 = *(const s16x8*)(oThi + off);
          const s16x8 bl1 = *(const s16x8*)(oTlo + off);
          s1 = __builtin_amdgcn_mfma_f32_16x16x32_bf16(alo[r][ks], bh1, s1, 0, 0, 0);
          s1 = __builtin_amdgcn_mfma_f32_16x16x32_bf16(ahi[r][ks], bl1, s1, 0, 0, 0);
          s1 = __builtin_amdgcn_mfma_f32_16x16x32_bf16(ahi[r][ks], bh1, s1, 0, 0, 0);
        }
        #pragma unroll
        for (int reg = 0; reg < 4; ++reg) {
          const int sl = kc * 4 + reg;
          const float nn = __shfl(nrm[r], sl);
          const float p = __expf(s1[reg] - nn - 2.772588722239781f);
          P[wid][r * 16 + sl][c * 16 + fr] = f2bf(p);
        }
      }
    __syncthreads();
    #pragma unroll
    for (int ks2 = 0; ks2 < 2; ++ks2) {
      s16x8 b2[5];
      #pragma unroll
      for (int nf = 0; nf < 5; ++nf)
        b2[nf] = *(const s16x8*)&KX[nf * 16 + fr][mc * 64 + ks2 * 32 + kc * 8];
      #pragma unroll
      for (int r = 0; r < 2; ++r) {
        const s16x8 a2 = *(const s16x8*)&P[wid][r * 16 + fr][ks2 * 32 + kc * 8];
        #pragma unroll
        for (int nf = 0; nf < 5; ++nf)
          acc2[r][nf] = __builtin_amdgcn_mfma_f32_16x16x32_bf16(a2, b2[nf], acc2[r][nf], 0, 0, 0);
      }
    }
  }
  #pragma unroll
  for (int r = 0; r < 2; ++r)
    #pragma unroll
    for (int reg = 0; reg < 4; ++reg) {
      const int s = ws0 + r * 16 + kc * 4 + reg;
      const float dv = __shfl(acc2[r][4][reg], lane & 48) + 1e-6f;
      #pragma unroll
      for (int nf = 0; nf < 4; ++nf)
        O[(size_t)(b * 4096 + s) * 1024 + h * 64 + nf * 16 + fr] =
            f2bf(acc2[r][nf][reg] / dv);
    }
}

// ======================== launcher ==========================================
extern "C" void kernel_launch(void* const* d_in, const int* in_sizes, int n_in,
                              void* d_out, int out_size, void* d_ws, size_t ws_size,
                              hipStream_t stream)
{
  const float* x      = (const float*)d_in[0];
  const float* conv_k = (const float*)d_in[1];
  const float* conv_b = (const float*)d_in[2];
  const float* rff_w  = (const float*)d_in[3];
  const float* rff_b  = (const float*)d_in[4];
  const float* proj_w = (const float*)d_in[5];
  const float* proj_b = (const float*)d_in[6];
  const float* omega  = (const float*)d_in[7];
  const float* lm     = (const float*)d_in[8];
  const float* out_w  = (const float*)d_in[9];
  const float* out_b  = (const float*)d_in[10];

  char* wsb = (char*)d_ws;
  size_t o = 0;
  auto alloc = [&](size_t bytes) {
    char* p = wsb + o;
    o = (o + bytes + 255) & ~(size_t)255;
    return p;
  };
  // --- region A: persistent (weights/tables)
  unsigned short* Wc_hi = (unsigned short*)alloc(4718592);
  unsigned short* Wc_lo = (unsigned short*)alloc(4718592);
  unsigned short* Wr_hi = (unsigned short*)alloc(4718592);
  unsigned short* Wr_lo = (unsigned short*)alloc(4718592);
  unsigned short* Wp    = (unsigned short*)alloc(4718592);
  unsigned short* Wo    = (unsigned short*)alloc(2097152);
  unsigned short* oThi  = (unsigned short*)alloc(32768);
  unsigned short* oTlo  = (unsigned short*)alloc(32768);
  float2* tab           = (float2*)alloc(1048576);
  // --- region B: xhi/xlo -> feats -> {VT, Obf, KVXT}
  char* RB = alloc(41943040);
  unsigned short* xhi   = (unsigned short*)RB;
  unsigned short* xlo   = (unsigned short*)(RB + 16777216);
  unsigned short* feats = (unsigned short*)RB;
  unsigned short* VT    = (unsigned short*)RB;
  unsigned short* Obf   = (unsigned short*)(RB + 20971520);
  unsigned short* KVXT  = (unsigned short*)(RB + 37748736);
  // --- region C: h hi/lo (3x) -> QKV f32 (3x)
  char* RC = alloc(100663296);
  unsigned short* hhi   = (unsigned short*)RC;
  unsigned short* hlo   = (unsigned short*)(RC + 50331648);
  float* QKV            = (float*)RC;
  // --- region E: kny + KVp
  float* kny = (float*)alloc(33554432);
  float* KVp = (float*)alloc(20971520);

  dim3 blk(256);
  split_prep_kernel<<<4096, blk, 0, stream>>>(x, xhi, xlo, 1048576);
  wconv_kernel<0><<<dim3(12, 16, 3), blk, 0, stream>>>(conv_k, Wc_hi, Wc_lo);
  wconv_kernel<1><<<dim3(16, 4, 9),  blk, 0, stream>>>(rff_w, Wr_hi, Wr_lo);
  wconv_kernel<2><<<dim3(12, 16, 3), blk, 0, stream>>>(proj_w, Wp, nullptr);
  wconv_kernel<3><<<dim3(16, 16, 1), blk, 0, stream>>>(out_w, Wo, nullptr);
  omega_prep_kernel<<<64, blk, 0, stream>>>(omega, oThi, oTlo);
  rope_table_kernel<<<512, blk, 0, stream>>>(tab);

  gemm_mfma<0><<<dim3(8, 64, 3), blk, 0, stream>>>(
      xhi, xlo, Wc_hi, Wc_lo, conv_b, nullptr,
      nullptr, hhi, hlo, 8192, 1024, 768);
  gemm_mfma<1><<<dim3(6, 64, 3), blk, 0, stream>>>(
      hhi, hlo, Wr_hi, Wr_lo, rff_b, nullptr,
      nullptr, feats, nullptr, 8192, 768, 1024);
  gemm_mfma<2><<<dim3(8, 64, 3), blk, 0, stream>>>(
      feats, nullptr, Wp, nullptr, proj_b, tab,
      QKV, nullptr, nullptr, 8192, 1024, 768);

  float* Qb = QKV;
  float* Kb = QKV + 8388608;
  float* Vb = QKV + 16777216;
  vt_kernel<<<dim3(32, 64), blk, 0, stream>>>(Vb, VT);
  nystrom_kernel<<<512, blk, 0, stream>>>(Kb, lm, kny);
  favor_k_mfma<<<256, dim3(512), 0, stream>>>(kny, oThi, oTlo, VT, KVp);
  reduce_kvxt_kernel<<<32, blk, 0, stream>>>(KVp, KVXT);
  favor_q_mfma<<<512, dim3(512), 0, stream>>>(Qb, oThi, oTlo, KVXT, Obf);
  gemm_mfma<3><<<dim3(8, 64), blk, 0, stream>>>(
      Obf, nullptr, Wo, nullptr, out_b, nullptr,
      (float*)d_out, nullptr, nullptr, 8192, 1024, 1024);
}

// Round 9
// 1057.868 us; speedup vs baseline: 1.1610x; 1.0793x over previous
//
#include <hip/hip_runtime.h>
#include <math.h>

// ---------------------------------------------------------------------------
// B=2, S=4096, C=1024, H=16, Dh=64, G=3, Ms=256, NRF=256, L=64
// Round 9: R8 + bijective chunked XCD swizzle in gemm_mfma (T1, m204):
// co-locates n-blocks sharing an A-panel on one XCD's L2 to kill the
// 8x A-panel HBM re-fetch measured in R8 (642MB vs ~40MB unique).
// ---------------------------------------------------------------------------

using f32x4 = __attribute__((ext_vector_type(4))) float;
using s16x8 = __attribute__((ext_vector_type(8))) short;

__device__ __forceinline__ unsigned short f2bf(float x) {
  unsigned u = __float_as_uint(x);
  unsigned r = u + 0x7fffu + ((u >> 16) & 1u);
  return (unsigned short)(r >> 16);
}
__device__ __forceinline__ float bf2f(unsigned short h) {
  return __uint_as_float(((unsigned)h) << 16);
}

// async global -> LDS, 16B per lane; lds dst is wave-uniform base + lane*16
__device__ __forceinline__ void gload16(const void* g, void* l) {
  __builtin_amdgcn_global_load_lds(
      (const __attribute__((address_space(1))) void*)g,
      (__attribute__((address_space(3))) void*)l, 16, 0, 0);
}

// ======================== f32 -> bf16 hi/lo splitter ========================
__global__ __launch_bounds__(256) void split_prep_kernel(
    const float* __restrict__ in, unsigned short* __restrict__ ohi,
    unsigned short* __restrict__ olo, int n8)
{
  const int i = blockIdx.x * 256 + threadIdx.x;
  if (i >= n8) return;
  const float4 f0 = ((const float4*)in)[i * 2];
  const float4 f1 = ((const float4*)in)[i * 2 + 1];
  const float v[8] = {f0.x, f0.y, f0.z, f0.w, f1.x, f1.y, f1.z, f1.w};
  s16x8 hi, lo;
  #pragma unroll
  for (int u = 0; u < 8; ++u) {
    const unsigned short hh = f2bf(v[u]);
    hi[u] = (short)hh;
    lo[u] = (short)f2bf(v[u] - bf2f(hh));
  }
  ((s16x8*)ohi)[i] = hi;
  ((s16x8*)olo)[i] = lo;
}

// ======================== weight transpose + convert ========================
template<int WM>  // 0 conv(3i, split) 1 rff(9 z=i*3+g, split) 2 proj(3i) 3 out_w
__global__ __launch_bounds__(256) void wconv_kernel(
    const float* __restrict__ in0, unsigned short* __restrict__ ohi,
    unsigned short* __restrict__ olo)
{
  int K, N;
  const float* in;
  unsigned short *oh, *ol = nullptr;
  const int z = blockIdx.z;
  if constexpr (WM == 0) {
    K = 768; N = 1024;
    in = in0 + (size_t)z * 786432;
    oh = ohi + (size_t)z * 786432; ol = olo + (size_t)z * 786432;
  } else if constexpr (WM == 1) {
    K = 1024; N = 256;
    const int i = z / 3, g = z % 3;
    in = in0 + (size_t)i * 786432 + (size_t)g * 262144;
    oh = ohi + (size_t)i * 786432 + (size_t)g * 262144;
    ol = olo + (size_t)i * 786432 + (size_t)g * 262144;
  } else if constexpr (WM == 2) {
    K = 768; N = 1024;
    in = in0 + (size_t)z * 786432; oh = ohi + (size_t)z * 786432;
  } else {
    K = 1024; N = 1024; in = in0; oh = ohi;
  }
  const int k0 = blockIdx.x * 64, n0 = blockIdx.y * 64;
  __shared__ float t[64][65];
  const int tid = threadIdx.x, tn = tid & 63, tr = tid >> 6;
  #pragma unroll 4
  for (int p = 0; p < 16; ++p) {
    const int kk = p * 4 + tr;
    t[kk][tn] = in[(size_t)(k0 + kk) * N + n0 + tn];
  }
  __syncthreads();
  #pragma unroll 4
  for (int p = 0; p < 16; ++p) {
    const int nn = p * 4 + tr;
    const float v = t[tn][nn];
    const unsigned short hi = f2bf(v);
    oh[(size_t)(n0 + nn) * K + k0 + tn] = hi;
    if constexpr (WM <= 1)
      ol[(size_t)(n0 + nn) * K + k0 + tn] = f2bf(v - bf2f(hi));
  }
}

// omega [64][256] f32 -> omegaT [256][64] bf16 hi/lo
__global__ __launch_bounds__(256) void omega_prep_kernel(
    const float* __restrict__ omega, unsigned short* __restrict__ oThi,
    unsigned short* __restrict__ oTlo)
{
  const int idx = blockIdx.x * 256 + threadIdx.x;  // 16384
  const int m = idx >> 6, d = idx & 63;
  const float v = omega[d * 256 + m];
  const unsigned short hi = f2bf(v);
  oThi[idx] = hi;
  oTlo[idx] = f2bf(v - bf2f(hi));
}

// V [8192][1024] f32 -> VT[bh][80][4096] bf16; rows 64..79: ksum row + zeros
__global__ __launch_bounds__(256) void vt_kernel(
    const float* __restrict__ V, unsigned short* __restrict__ VT)
{
  const int bh = blockIdx.x, sb = blockIdx.y;
  const int b = bh >> 4, h = bh & 15;
  __shared__ float t[64][65];
  const int tid = threadIdx.x, tn = tid & 63, tr = tid >> 6;
  #pragma unroll 4
  for (int p = 0; p < 16; ++p)
    t[p * 4 + tr][tn] =
        V[(size_t)(b * 4096 + sb * 64 + p * 4 + tr) * 1024 + h * 64 + tn];
  __syncthreads();
  #pragma unroll 4
  for (int p = 0; p < 16; ++p)
    VT[((size_t)bh * 80 + p * 4 + tr) * 4096 + sb * 64 + tn] =
        f2bf(t[tn][p * 4 + tr]);
  #pragma unroll
  for (int p = 0; p < 4; ++p) {
    const int rr = p * 4 + tr;
    VT[((size_t)bh * 80 + 64 + rr) * 4096 + sb * 64 + tn] =
        (rr == 0) ? 0x3F80 : 0;
  }
}

// ======================== MFMA GEMM (XCD-swizzled) ==========================
// 128x128 tile, BK=32, 256 threads (2x2 waves), 16x16x32 bf16 MFMA.
// Block coords derived via bijective chunked XCD remap (m204): hw linear id L
// -> logical = (L&7)*(nwg/8) + (L>>3); decompose x-fastest. Requires
// nwg % 8 == 0 (all grids here: 1536/1152/1536/512).
template<int MODE>
__global__ __launch_bounds__(256, MODE >= 2 ? 4 : 3) void gemm_mfma(
    const unsigned short* __restrict__ Ahi, const unsigned short* __restrict__ Alo,
    const unsigned short* __restrict__ Bhig, const unsigned short* __restrict__ Blog,
    const float* __restrict__ bias, const float2* __restrict__ tab,
    float* __restrict__ Cf, unsigned short* __restrict__ C1,
    unsigned short* __restrict__ C2,
    int M, int N, int K)
{
  constexpr bool SPLIT = (MODE <= 1);
  __shared__ alignas(16) char smem[SPLIT ? 32768 : 16384];
  char* const sAhi = smem;
  char* const sBhi = smem + (SPLIT ? 16384 : 8192);
  char* const sAlo = smem + 8192;
  char* const sBlo = smem + 24576;

  // ---- XCD chunked remap ----
  const int gx = gridDim.x, gy = gridDim.y;
  const int L = blockIdx.x + gx * (blockIdx.y + gy * blockIdx.z);
  const int nwg = gx * gy * gridDim.z;
  const int logical = (L & 7) * (nwg >> 3) + (L >> 3);
  const int bx = logical % gx;
  const int by = (logical / gx) % gy;
  const int z = logical / (gx * gy);

  if constexpr (MODE == 0) {
    Bhig += (size_t)z * 786432; Blog += (size_t)z * 786432;
    bias += z * 1024;
    C1 += (size_t)z * 8388608; C2 += (size_t)z * 8388608;
  } else if constexpr (MODE == 1) {
    Ahi += (size_t)z * 8388608; Alo += (size_t)z * 8388608;
    Bhig += (size_t)z * 786432; Blog += (size_t)z * 786432;
    bias += z * 768;
    C1 += (size_t)z * 6291456;
  } else if constexpr (MODE == 2) {
    Ahi += (size_t)z * 6291456;
    Bhig += (size_t)z * 786432;
    bias += z * 1024;
    Cf += (size_t)z * 8388608;
  }

  const int tid = threadIdx.x;
  const int n0 = bx * 128;
  const int m0 = by * 128;

  const int lane = tid & 63, wid = tid >> 6;
  const int wr = wid >> 1, wc = wid & 1;
  const int fr = lane & 15, kc = lane >> 4;
  const int fsw = ((fr >> 1) & 3) << 4;

  // DMA staging geometry (see R8)
  const int seg0 = wid * 2;
  const int r0 = seg0 * 16 + (lane >> 2);
  const int r1 = r0 + 16;
  const int cp = lane & 3;
  const int c0e = (cp ^ ((r0 >> 1) & 3)) * 8;
  const int c1e = (cp ^ ((r1 >> 1) & 3)) * 8;
  char* const dA0 = sAhi + seg0 * 1024;  char* const dA1 = dA0 + 1024;
  char* const dL0 = sAlo + seg0 * 1024;  char* const dL1 = dL0 + 1024;
  char* const dB0 = sBhi + seg0 * 1024;  char* const dB1 = dB0 + 1024;
  char* const dBl0 = sBlo + seg0 * 1024; char* const dBl1 = dBl0 + 1024;

  f32x4 acc[4][4];
  #pragma unroll
  for (int i = 0; i < 4; ++i)
    #pragma unroll
    for (int j = 0; j < 4; ++j) acc[i][j] = f32x4{0.f, 0.f, 0.f, 0.f};

  for (int k0 = 0; k0 < K; k0 += 32) {
    __syncthreads();   // WAR: prior tile's ds_reads complete before DMA lands
    if constexpr (MODE == 0) {
      const int t = k0 >> 8;
      const int cb = (n0 >> 8) * 256 + (k0 & 255);
      const int g0 = m0 + r0, g1 = m0 + r1;
      int s0 = (g0 & 4095) + t - 1; s0 = s0 < 0 ? 0 : (s0 > 4095 ? 4095 : s0);
      int s1 = (g1 & 4095) + t - 1; s1 = s1 < 0 ? 0 : (s1 > 4095 ? 4095 : s1);
      const size_t o0 = ((size_t)((g0 >> 12) * 4096 + s0)) * 1024 + cb;
      const size_t o1 = ((size_t)((g1 >> 12) * 4096 + s1)) * 1024 + cb;
      gload16(Ahi + o0 + c0e, dA0);
      gload16(Ahi + o1 + c1e, dA1);
      gload16(Alo + o0 + c0e, dL0);
      gload16(Alo + o1 + c1e, dL1);
    } else {
      const size_t o0 = (size_t)(m0 + r0) * K + k0;
      const size_t o1 = (size_t)(m0 + r1) * K + k0;
      gload16(Ahi + o0 + c0e, dA0);
      gload16(Ahi + o1 + c1e, dA1);
      if constexpr (SPLIT) {
        gload16(Alo + o0 + c0e, dL0);
        gload16(Alo + o1 + c1e, dL1);
      }
    }
    {
      const size_t o0 = (size_t)(n0 + r0) * K + k0;
      const size_t o1 = (size_t)(n0 + r1) * K + k0;
      gload16(Bhig + o0 + c0e, dB0);
      gload16(Bhig + o1 + c1e, dB1);
      if constexpr (SPLIT) {
        gload16(Blog + o0 + c0e, dBl0);
        gload16(Blog + o1 + c1e, dBl1);
      }
    }
    __syncthreads();   // drains vmcnt(0): tile staged

    if constexpr (MODE == 0) {
      const int t = k0 >> 8;
      int zr = -1;
      if (t == 0 && (m0 & 4095) == 0) zr = 0;
      if (t == 2 && (m0 & 4095) == 3968) zr = 127;
      if (zr >= 0) {
        if (tid < 8) {
          char* buf = (tid < 4) ? sAhi : sAlo;
          *(s16x8*)(buf + zr * 64 + (tid & 3) * 16) = s16x8{0,0,0,0,0,0,0,0};
        }
        __syncthreads();
      }
    }

    s16x8 Af[4], Al[4], Bf[4], Bl[4];
    #pragma unroll
    for (int i = 0; i < 4; ++i) {
      const int off = (wr * 64 + i * 16 + fr) * 64 + ((kc * 16) ^ fsw);
      Af[i] = *(const s16x8*)(sAhi + off);
      if constexpr (SPLIT) Al[i] = *(const s16x8*)(sAlo + off);
    }
    #pragma unroll
    for (int j = 0; j < 4; ++j) {
      const int off = (wc * 64 + j * 16 + fr) * 64 + ((kc * 16) ^ fsw);
      Bf[j] = *(const s16x8*)(sBhi + off);
      if constexpr (SPLIT) Bl[j] = *(const s16x8*)(sBlo + off);
    }
    #pragma unroll
    for (int i = 0; i < 4; ++i)
      #pragma unroll
      for (int j = 0; j < 4; ++j) {
        acc[i][j] = __builtin_amdgcn_mfma_f32_16x16x32_bf16(Af[i], Bf[j], acc[i][j], 0, 0, 0);
        if constexpr (SPLIT) {
          acc[i][j] = __builtin_amdgcn_mfma_f32_16x16x32_bf16(Af[i], Bl[j], acc[i][j], 0, 0, 0);
          acc[i][j] = __builtin_amdgcn_mfma_f32_16x16x32_bf16(Al[i], Bf[j], acc[i][j], 0, 0, 0);
        }
      }
  }

  // ---- epilogue ----
  if constexpr (MODE == 2) {
    #pragma unroll
    for (int i = 0; i < 4; ++i)
      #pragma unroll
      for (int j2 = 0; j2 < 2; ++j2) {
        const int col0 = n0 + wc * 64 + j2 * 16 + fr;
        const int jr = col0 & 31;
        const float b0 = bias[col0], b1 = bias[col0 + 32];
        #pragma unroll
        for (int rr = 0; rr < 4; ++rr) {
          const int row = m0 + wr * 64 + i * 16 + kc * 4 + rr;
          float v0 = acc[i][j2][rr] + b0;
          float v1 = acc[i][j2 + 2][rr] + b1;
          if (z < 2) {
            const float2 cs = tab[((row & 4095) << 5) | jr];
            const float rr0 = v0 * cs.x - v1 * cs.y;
            const float rr1 = v1 * cs.x + v0 * cs.y;
            v0 = rr0; v1 = rr1;
          }
          Cf[(size_t)row * N + col0] = v0;
          Cf[(size_t)row * N + col0 + 32] = v1;
        }
      }
  } else {
    #pragma unroll
    for (int i = 0; i < 4; ++i)
      #pragma unroll
      for (int j = 0; j < 4; ++j) {
        const int col = n0 + wc * 64 + j * 16 + fr;
        #pragma unroll
        for (int rr = 0; rr < 4; ++rr) {
          const int row = m0 + wr * 64 + i * 16 + kc * 4 + rr;
          const float v = acc[i][j][rr];
          if constexpr (MODE == 0) {
            const float hv = v + bias[col];
            const unsigned short hh = f2bf(hv);
            C1[(size_t)row * N + col] = hh;
            C2[(size_t)row * N + col] = f2bf(hv - bf2f(hh));
          } else if constexpr (MODE == 1) {
            const int g = col >> 8;
            const float sg = (g == 0) ? 1.0f : ((g == 1) ? 1.41421356237309515f : 2.0f);
            const float zc = cosf(v * sg + bias[col]) * 0.08838834764831845f;
            C1[(size_t)row * N + col] = f2bf(zc);
          } else {
            Cf[(size_t)row * N + col] = v + bias[col];
          }
        }
      }
  }
}

// ======================== RoPE table ========================================
__global__ __launch_bounds__(256) void rope_table_kernel(float2* __restrict__ tab)
{
  const int idx = blockIdx.x * 256 + threadIdx.x;
  const int j = idx & 31, s = idx >> 5;
  const double inv = pow(10000.0, -(double)j * (1.0 / 32.0));
  double sd, cd;
  sincos((double)s * inv, &sd, &cd);
  tab[idx] = make_float2((float)cd, (float)sd);
}

// ======================== Nystrom RBF features ==============================
__global__ __launch_bounds__(256) void nystrom_kernel(
    const float* __restrict__ Kb, const float* __restrict__ lm,
    float* __restrict__ kny)
{
  __shared__ float lmT[64][65];
  __shared__ float lnorm[64];
  const int tid = threadIdx.x;
  for (int idx = tid; idx < 4096; idx += 256)
    lmT[idx & 63][idx >> 6] = lm[idx];
  if (tid < 64) {
    float s = 0.f;
    #pragma unroll
    for (int d = 0; d < 64; ++d) { const float v = lm[tid * 64 + d]; s = fmaf(v, v, s); }
    lnorm[tid] = s;
  }
  __syncthreads();
  const int lane = tid & 63;
  const int nw = gridDim.x * 4;
  for (int row = blockIdx.x * 4 + (tid >> 6); row < 131072; row += nw) {
    const float kd = Kb[(size_t)row * 64 + lane];
    float nk = kd * kd;
    #pragma unroll
    for (int o = 32; o > 0; o >>= 1) nk += __shfl_xor(nk, o, 64);
    float dot = 0.f;
    #pragma unroll
    for (int d = 0; d < 64; ++d) dot = fmaf(__shfl(kd, d, 64), lmT[d][lane], dot);
    kny[(size_t)row * 64 + lane] = __expf((2.f * dot - nk - lnorm[lane]) * 0.015625f);
  }
}

// ======================== FAVOR-K (MFMA) ====================================
__global__ __launch_bounds__(512) void favor_k_mfma(
    const float* __restrict__ kny,
    const unsigned short* __restrict__ oThi, const unsigned short* __restrict__ oTlo,
    const unsigned short* __restrict__ VT, float* __restrict__ KVp)
{
  const int bid = blockIdx.x;
  const int bh = bid >> 3, chunk = bid & 7;
  const int b = bh >> 4, h = bh & 15;
  const int s0 = chunk * 512;
  const int tid = threadIdx.x, lane = tid & 63, wid = tid >> 6;
  const int fr = lane & 15, kc = lane >> 4;
  const int m0w = wid * 32;

  __shared__ unsigned short P[256][40];
  __shared__ float T[8][32][84];

  s16x8 whi[2][2], wlo[2][2];
  #pragma unroll
  for (int c = 0; c < 2; ++c)
    #pragma unroll
    for (int ks = 0; ks < 2; ++ks) {
      const size_t off = (size_t)(m0w + c * 16 + fr) * 64 + ks * 32 + kc * 8;
      whi[c][ks] = *(const s16x8*)(oThi + off);
      wlo[c][ks] = *(const s16x8*)(oTlo + off);
    }

  f32x4 acc2[2][5];
  #pragma unroll
  for (int i = 0; i < 2; ++i)
    #pragma unroll
    for (int j = 0; j < 5; ++j) acc2[i][j] = f32x4{0.f, 0.f, 0.f, 0.f};

  for (int st = 0; st < 512; st += 32) {
    s16x8 ahi[2][2], alo[2][2];
    float nrm[2];
    #pragma unroll
    for (int r = 0; r < 2; ++r) {
      float part = 0.f;
      #pragma unroll
      for (int ks = 0; ks < 2; ++ks) {
        const float* ap = kny +
            ((size_t)((b * 4096 + s0 + st + r * 16 + fr) * 16 + h)) * 64 + ks * 32 + kc * 8;
        const float4 f0 = ((const float4*)ap)[0];
        const float4 f1 = ((const float4*)ap)[1];
        float v[8] = {f0.x, f0.y, f0.z, f0.w, f1.x, f1.y, f1.z, f1.w};
        #pragma unroll
        for (int u = 0; u < 8; ++u) {
          part = fmaf(v[u], v[u], part);
          const unsigned short hh = f2bf(v[u]);
          ahi[r][ks][u] = (short)hh;
          alo[r][ks][u] = (short)f2bf(v[u] - bf2f(hh));
        }
      }
      part += __shfl_xor(part, 16);
      part += __shfl_xor(part, 32);
      nrm[r] = 0.5f * part;
    }
    __syncthreads();
    #pragma unroll
    for (int r = 0; r < 2; ++r)
      #pragma unroll
      for (int c = 0; c < 2; ++c) {
        f32x4 s1 = f32x4{0.f, 0.f, 0.f, 0.f};
        #pragma unroll
        for (int ks = 0; ks < 2; ++ks) {
          s1 = __builtin_amdgcn_mfma_f32_16x16x32_bf16(alo[r][ks], whi[c][ks], s1, 0, 0, 0);
          s1 = __builtin_amdgcn_mfma_f32_16x16x32_bf16(ahi[r][ks], wlo[c][ks], s1, 0, 0, 0);
          s1 = __builtin_amdgcn_mfma_f32_16x16x32_bf16(ahi[r][ks], whi[c][ks], s1, 0, 0, 0);
        }
        #pragma unroll
        for (int reg = 0; reg < 4; ++reg) {
          const int sl = kc * 4 + reg;
          const float nn = __shfl(nrm[r], sl);
          const float p = __expf(s1[reg] - nn - 2.772588722239781f);
          P[m0w + c * 16 + fr][r * 16 + sl] = f2bf(p);
        }
      }
    __syncthreads();
    s16x8 b2[5];
    #pragma unroll
    for (int nf = 0; nf < 5; ++nf)
      b2[nf] = *(const s16x8*)(VT + ((size_t)bh * 80 + nf * 16 + fr) * 4096 +
                               s0 + st + kc * 8);
    #pragma unroll
    for (int mf = 0; mf < 2; ++mf) {
      const s16x8 a2 = *(const s16x8*)&P[m0w + mf * 16 + fr][kc * 8];
      #pragma unroll
      for (int nf = 0; nf < 5; ++nf)
        acc2[mf][nf] = __builtin_amdgcn_mfma_f32_16x16x32_bf16(a2, b2[nf], acc2[mf][nf], 0, 0, 0);
    }
  }
  #pragma unroll
  for (int mf = 0; mf < 2; ++mf)
    #pragma unroll
    for (int nf = 0; nf < 5; ++nf)
      #pragma unroll
      for (int reg = 0; reg < 4; ++reg)
        T[wid][mf * 16 + kc * 4 + reg][nf * 16 + fr] = acc2[mf][nf][reg];
  __syncthreads();
  #pragma unroll
  for (int i = 0; i < 40; ++i) {
    const int flat = i * 64 + lane;
    const int n = flat >> 5, ml = flat & 31;
    KVp[((size_t)bid * 80 + n) * 256 + m0w + ml] = T[wid][ml][n];
  }
}

// ======================== reduce KVp -> KVXT bf16 ===========================
__global__ __launch_bounds__(256) void reduce_kvxt_kernel(
    const float* __restrict__ KVp, unsigned short* __restrict__ KVXT)
{
  const int bh = blockIdx.x;
  const int m = threadIdx.x;
  for (int n = 0; n < 80; ++n) {
    float s = 0.f;
    #pragma unroll
    for (int c = 0; c < 8; ++c)
      s += KVp[((size_t)(bh * 8 + c) * 80 + n) * 256 + m];
    KVXT[((size_t)bh * 80 + n) * 256 + m] = f2bf(s);
  }
}

// ======================== FAVOR-Q (MFMA) ====================================
__global__ __launch_bounds__(512) void favor_q_mfma(
    const float* __restrict__ Q,
    const unsigned short* __restrict__ oThi, const unsigned short* __restrict__ oTlo,
    const unsigned short* __restrict__ KVXT, unsigned short* __restrict__ O)
{
  const int bid = blockIdx.x;
  const int bh = bid >> 4, chunk = bid & 15;
  const int b = bh >> 4, h = bh & 15;
  const int s0 = chunk * 256;
  const int tid = threadIdx.x, lane = tid & 63, wid = tid >> 6;
  const int fr = lane & 15, kc = lane >> 4;
  const int ws0 = s0 + wid * 32;

  __shared__ unsigned short KX[80][264];
  __shared__ unsigned short P[8][32][66];

  for (int i = tid; i < 80 * 256; i += 512)
    KX[i >> 8][i & 255] = KVXT[(size_t)bh * 80 * 256 + i];
  __syncthreads();

  s16x8 ahi[2][2], alo[2][2];
  float nrm[2];
  #pragma unroll
  for (int r = 0; r < 2; ++r) {
    float part = 0.f;
    #pragma unroll
    for (int ks = 0; ks < 2; ++ks) {
      const float* ap = Q + ((size_t)(b * 4096 + ws0 + r * 16 + fr)) * 1024 +
                        h * 64 + ks * 32 + kc * 8;
      const float4 f0 = ((const float4*)ap)[0];
      const float4 f1 = ((const float4*)ap)[1];
      float v[8] = {f0.x, f0.y, f0.z, f0.w, f1.x, f1.y, f1.z, f1.w};
      #pragma unroll
      for (int u = 0; u < 8; ++u) {
        part = fmaf(v[u], v[u], part);
        const unsigned short hh = f2bf(v[u]);
        ahi[r][ks][u] = (short)hh;
        alo[r][ks][u] = (short)f2bf(v[u] - bf2f(hh));
      }
    }
    part += __shfl_xor(part, 16);
    part += __shfl_xor(part, 32);
    nrm[r] = 0.5f * part;
  }

  f32x4 acc2[2][5];
  #pragma unroll
  for (int i = 0; i < 2; ++i)
    #pragma unroll
    for (int j = 0; j < 5; ++j) acc2[i][j] = f32x4{0.f, 0.f, 0.f, 0.f};

  for (int mc = 0; mc < 4; ++mc) {
    __syncthreads();
    #pragma unroll
    for (int r = 0; r < 2; ++r)
      #pragma unroll
      for (int c = 0; c < 4; ++c) {
        f32x4 s1 = f32x4{0.f, 0.f, 0.f, 0.f};
        #pragma unroll
        for (int ks = 0; ks < 2; ++ks) {
          const size_t off = (size_t)(mc * 64 + c * 16 + fr) * 64 + ks * 32 + kc * 8;
          const s16x8 bh1 = *(const s16x8*)(oThi + off);
          const s16x8 bl1 = *(const s16x8*)(oTlo + off);
          s1 = __builtin_amdgcn_mfma_f32_16x16x32_bf16(alo[r][ks], bh1, s1, 0, 0, 0);
          s1 = __builtin_amdgcn_mfma_f32_16x16x32_bf16(ahi[r][ks], bl1, s1, 0, 0, 0);
          s1 = __builtin_amdgcn_mfma_f32_16x16x32_bf16(ahi[r][ks], bh1, s1, 0, 0, 0);
        }
        #pragma unroll
        for (int reg = 0; reg < 4; ++reg) {
          const int sl = kc * 4 + reg;
          const float nn = __shfl(nrm[r], sl);
          const float p = __expf(s1[reg] - nn - 2.772588722239781f);
          P[wid][r * 16 + sl][c * 16 + fr] = f2bf(p);
        }
      }
    __syncthreads();
    #pragma unroll
    for (int ks2 = 0; ks2 < 2; ++ks2) {
      s16x8 b2[5];
      #pragma unroll
      for (int nf = 0; nf < 5; ++nf)
        b2[nf] = *(const s16x8*)&KX[nf * 16 + fr][mc * 64 + ks2 * 32 + kc * 8];
      #pragma unroll
      for (int r = 0; r < 2; ++r) {
        const s16x8 a2 = *(const s16x8*)&P[wid][r * 16 + fr][ks2 * 32 + kc * 8];
        #pragma unroll
        for (int nf = 0; nf < 5; ++nf)
          acc2[r][nf] = __builtin_amdgcn_mfma_f32_16x16x32_bf16(a2, b2[nf], acc2[r][nf], 0, 0, 0);
      }
    }
  }
  #pragma unroll
  for (int r = 0; r < 2; ++r)
    #pragma unroll
    for (int reg = 0; reg < 4; ++reg) {
      const int s = ws0 + r * 16 + kc * 4 + reg;
      const float dv = __shfl(acc2[r][4][reg], lane & 48) + 1e-6f;
      #pragma unroll
      for (int nf = 0; nf < 4; ++nf)
        O[(size_t)(b * 4096 + s) * 1024 + h * 64 + nf * 16 + fr] =
            f2bf(acc2[r][nf][reg] / dv);
    }
}

// ======================== launcher ==========================================
extern "C" void kernel_launch(void* const* d_in, const int* in_sizes, int n_in,
                              void* d_out, int out_size, void* d_ws, size_t ws_size,
                              hipStream_t stream)
{
  const float* x      = (const float*)d_in[0];
  const float* conv_k = (const float*)d_in[1];
  const float* conv_b = (const float*)d_in[2];
  const float* rff_w  = (const float*)d_in[3];
  const float* rff_b  = (const float*)d_in[4];
  const float* proj_w = (const float*)d_in[5];
  const float* proj_b = (const float*)d_in[6];
  const float* omega  = (const float*)d_in[7];
  const float* lm     = (const float*)d_in[8];
  const float* out_w  = (const float*)d_in[9];
  const float* out_b  = (const float*)d_in[10];

  char* wsb = (char*)d_ws;
  size_t o = 0;
  auto alloc = [&](size_t bytes) {
    char* p = wsb + o;
    o = (o + bytes + 255) & ~(size_t)255;
    return p;
  };
  // --- region A: persistent (weights/tables)
  unsigned short* Wc_hi = (unsigned short*)alloc(4718592);
  unsigned short* Wc_lo = (unsigned short*)alloc(4718592);
  unsigned short* Wr_hi = (unsigned short*)alloc(4718592);
  unsigned short* Wr_lo = (unsigned short*)alloc(4718592);
  unsigned short* Wp    = (unsigned short*)alloc(4718592);
  unsigned short* Wo    = (unsigned short*)alloc(2097152);
  unsigned short* oThi  = (unsigned short*)alloc(32768);
  unsigned short* oTlo  = (unsigned short*)alloc(32768);
  float2* tab           = (float2*)alloc(1048576);
  // --- region B: xhi/xlo -> feats -> {VT, Obf, KVXT}
  char* RB = alloc(41943040);
  unsigned short* xhi   = (unsigned short*)RB;
  unsigned short* xlo   = (unsigned short*)(RB + 16777216);
  unsigned short* feats = (unsigned short*)RB;
  unsigned short* VT    = (unsigned short*)RB;
  unsigned short* Obf   = (unsigned short*)(RB + 20971520);
  unsigned short* KVXT  = (unsigned short*)(RB + 37748736);
  // --- region C: h hi/lo (3x) -> QKV f32 (3x)
  char* RC = alloc(100663296);
  unsigned short* hhi   = (unsigned short*)RC;
  unsigned short* hlo   = (unsigned short*)(RC + 50331648);
  float* QKV            = (float*)RC;
  // --- region E: kny + KVp
  float* kny = (float*)alloc(33554432);
  float* KVp = (float*)alloc(20971520);

  dim3 blk(256);
  split_prep_kernel<<<4096, blk, 0, stream>>>(x, xhi, xlo, 1048576);
  wconv_kernel<0><<<dim3(12, 16, 3), blk, 0, stream>>>(conv_k, Wc_hi, Wc_lo);
  wconv_kernel<1><<<dim3(16, 4, 9),  blk, 0, stream>>>(rff_w, Wr_hi, Wr_lo);
  wconv_kernel<2><<<dim3(12, 16, 3), blk, 0, stream>>>(proj_w, Wp, nullptr);
  wconv_kernel<3><<<dim3(16, 16, 1), blk, 0, stream>>>(out_w, Wo, nullptr);
  omega_prep_kernel<<<64, blk, 0, stream>>>(omega, oThi, oTlo);
  rope_table_kernel<<<512, blk, 0, stream>>>(tab);

  gemm_mfma<0><<<dim3(8, 64, 3), blk, 0, stream>>>(
      xhi, xlo, Wc_hi, Wc_lo, conv_b, nullptr,
      nullptr, hhi, hlo, 8192, 1024, 768);
  gemm_mfma<1><<<dim3(6, 64, 3), blk, 0, stream>>>(
      hhi, hlo, Wr_hi, Wr_lo, rff_b, nullptr,
      nullptr, feats, nullptr, 8192, 768, 1024);
  gemm_mfma<2><<<dim3(8, 64, 3), blk, 0, stream>>>(
      feats, nullptr, Wp, nullptr, proj_b, tab,
      QKV, nullptr, nullptr, 8192, 1024, 768);

  float* Qb = QKV;
  float* Kb = QKV + 8388608;
  float* Vb = QKV + 16777216;
  vt_kernel<<<dim3(32, 64), blk, 0, stream>>>(Vb, VT);
  nystrom_kernel<<<512, blk, 0, stream>>>(Kb, lm, kny);
  favor_k_mfma<<<256, dim3(512), 0, stream>>>(kny, oThi, oTlo, VT, KVp);
  reduce_kvxt_kernel<<<32, blk, 0, stream>>>(KVp, KVXT);
  favor_q_mfma<<<512, dim3(512), 0, stream>>>(Qb, oThi, oTlo, KVXT, Obf);
  gemm_mfma<3><<<dim3(8, 64), blk, 0, stream>>>(
      Obf, nullptr, Wo, nullptr, out_b, nullptr,
      (float*)d_out, nullptr, nullptr, 8192, 1024, 1024);
}

// Round 10
// 925.294 us; speedup vs baseline: 1.3273x; 1.1433x over previous
//
#include <hip/hip_runtime.h>
#include <math.h>

// ---------------------------------------------------------------------------
// B=2, S=4096, C=1024, H=16, Dh=64, G=3, Ms=256, NRF=256, L=64
// Round 10: R9 + (1) favor MFMA1 single-term plain-bf16 (q/kny rms~0.06 ->
// split unnecessary), (2) nystrom MFMA-ized, emits bf16 kny + knorm,
// (3) split-GEMM launch_bounds 3->4.
// ---------------------------------------------------------------------------

using f32x4 = __attribute__((ext_vector_type(4))) float;
using s16x8 = __attribute__((ext_vector_type(8))) short;

__device__ __forceinline__ unsigned short f2bf(float x) {
  unsigned u = __float_as_uint(x);
  unsigned r = u + 0x7fffu + ((u >> 16) & 1u);
  return (unsigned short)(r >> 16);
}
__device__ __forceinline__ float bf2f(unsigned short h) {
  return __uint_as_float(((unsigned)h) << 16);
}

// async global -> LDS, 16B per lane; lds dst is wave-uniform base + lane*16
__device__ __forceinline__ void gload16(const void* g, void* l) {
  __builtin_amdgcn_global_load_lds(
      (const __attribute__((address_space(1))) void*)g,
      (__attribute__((address_space(3))) void*)l, 16, 0, 0);
}

// ======================== f32 -> bf16 hi/lo splitter ========================
__global__ __launch_bounds__(256) void split_prep_kernel(
    const float* __restrict__ in, unsigned short* __restrict__ ohi,
    unsigned short* __restrict__ olo, int n8)
{
  const int i = blockIdx.x * 256 + threadIdx.x;
  if (i >= n8) return;
  const float4 f0 = ((const float4*)in)[i * 2];
  const float4 f1 = ((const float4*)in)[i * 2 + 1];
  const float v[8] = {f0.x, f0.y, f0.z, f0.w, f1.x, f1.y, f1.z, f1.w};
  s16x8 hi, lo;
  #pragma unroll
  for (int u = 0; u < 8; ++u) {
    const unsigned short hh = f2bf(v[u]);
    hi[u] = (short)hh;
    lo[u] = (short)f2bf(v[u] - bf2f(hh));
  }
  ((s16x8*)ohi)[i] = hi;
  ((s16x8*)olo)[i] = lo;
}

// ======================== weight transpose + convert ========================
template<int WM>  // 0 conv(3i, split) 1 rff(9 z=i*3+g, split) 2 proj(3i) 3 out_w
__global__ __launch_bounds__(256) void wconv_kernel(
    const float* __restrict__ in0, unsigned short* __restrict__ ohi,
    unsigned short* __restrict__ olo)
{
  int K, N;
  const float* in;
  unsigned short *oh, *ol = nullptr;
  const int z = blockIdx.z;
  if constexpr (WM == 0) {
    K = 768; N = 1024;
    in = in0 + (size_t)z * 786432;
    oh = ohi + (size_t)z * 786432; ol = olo + (size_t)z * 786432;
  } else if constexpr (WM == 1) {
    K = 1024; N = 256;
    const int i = z / 3, g = z % 3;
    in = in0 + (size_t)i * 786432 + (size_t)g * 262144;
    oh = ohi + (size_t)i * 786432 + (size_t)g * 262144;
    ol = olo + (size_t)i * 786432 + (size_t)g * 262144;
  } else if constexpr (WM == 2) {
    K = 768; N = 1024;
    in = in0 + (size_t)z * 786432; oh = ohi + (size_t)z * 786432;
  } else {
    K = 1024; N = 1024; in = in0; oh = ohi;
  }
  const int k0 = blockIdx.x * 64, n0 = blockIdx.y * 64;
  __shared__ float t[64][65];
  const int tid = threadIdx.x, tn = tid & 63, tr = tid >> 6;
  #pragma unroll 4
  for (int p = 0; p < 16; ++p) {
    const int kk = p * 4 + tr;
    t[kk][tn] = in[(size_t)(k0 + kk) * N + n0 + tn];
  }
  __syncthreads();
  #pragma unroll 4
  for (int p = 0; p < 16; ++p) {
    const int nn = p * 4 + tr;
    const float v = t[tn][nn];
    const unsigned short hi = f2bf(v);
    oh[(size_t)(n0 + nn) * K + k0 + tn] = hi;
    if constexpr (WM <= 1)
      ol[(size_t)(n0 + nn) * K + k0 + tn] = f2bf(v - bf2f(hi));
  }
}

// omega [64][256] f32 -> omegaT [256][64] bf16 (hi only used downstream)
__global__ __launch_bounds__(256) void omega_prep_kernel(
    const float* __restrict__ omega, unsigned short* __restrict__ oThi)
{
  const int idx = blockIdx.x * 256 + threadIdx.x;  // 16384
  const int m = idx >> 6, d = idx & 63;
  oThi[idx] = f2bf(omega[d * 256 + m]);
}

// V [8192][1024] f32 -> VT[bh][80][4096] bf16; rows 64..79: ksum row + zeros
__global__ __launch_bounds__(256) void vt_kernel(
    const float* __restrict__ V, unsigned short* __restrict__ VT)
{
  const int bh = blockIdx.x, sb = blockIdx.y;
  const int b = bh >> 4, h = bh & 15;
  __shared__ float t[64][65];
  const int tid = threadIdx.x, tn = tid & 63, tr = tid >> 6;
  #pragma unroll 4
  for (int p = 0; p < 16; ++p)
    t[p * 4 + tr][tn] =
        V[(size_t)(b * 4096 + sb * 64 + p * 4 + tr) * 1024 + h * 64 + tn];
  __syncthreads();
  #pragma unroll 4
  for (int p = 0; p < 16; ++p)
    VT[((size_t)bh * 80 + p * 4 + tr) * 4096 + sb * 64 + tn] =
        f2bf(t[tn][p * 4 + tr]);
  #pragma unroll
  for (int p = 0; p < 4; ++p) {
    const int rr = p * 4 + tr;
    VT[((size_t)bh * 80 + 64 + rr) * 4096 + sb * 64 + tn] =
        (rr == 0) ? 0x3F80 : 0;
  }
}

// ======================== MFMA GEMM (XCD-swizzled) ==========================
template<int MODE>
__global__ __launch_bounds__(256, 4) void gemm_mfma(
    const unsigned short* __restrict__ Ahi, const unsigned short* __restrict__ Alo,
    const unsigned short* __restrict__ Bhig, const unsigned short* __restrict__ Blog,
    const float* __restrict__ bias, const float2* __restrict__ tab,
    float* __restrict__ Cf, unsigned short* __restrict__ C1,
    unsigned short* __restrict__ C2,
    int M, int N, int K)
{
  constexpr bool SPLIT = (MODE <= 1);
  __shared__ alignas(16) char smem[SPLIT ? 32768 : 16384];
  char* const sAhi = smem;
  char* const sBhi = smem + (SPLIT ? 16384 : 8192);
  char* const sAlo = smem + 8192;
  char* const sBlo = smem + 24576;

  // ---- XCD chunked remap (bijective; nwg % 8 == 0 for all grids) ----
  const int gx = gridDim.x, gy = gridDim.y;
  const int L = blockIdx.x + gx * (blockIdx.y + gy * blockIdx.z);
  const int nwg = gx * gy * gridDim.z;
  const int logical = (L & 7) * (nwg >> 3) + (L >> 3);
  const int bx = logical % gx;
  const int by = (logical / gx) % gy;
  const int z = logical / (gx * gy);

  if constexpr (MODE == 0) {
    Bhig += (size_t)z * 786432; Blog += (size_t)z * 786432;
    bias += z * 1024;
    C1 += (size_t)z * 8388608; C2 += (size_t)z * 8388608;
  } else if constexpr (MODE == 1) {
    Ahi += (size_t)z * 8388608; Alo += (size_t)z * 8388608;
    Bhig += (size_t)z * 786432; Blog += (size_t)z * 786432;
    bias += z * 768;
    C1 += (size_t)z * 6291456;
  } else if constexpr (MODE == 2) {
    Ahi += (size_t)z * 6291456;
    Bhig += (size_t)z * 786432;
    bias += z * 1024;
    Cf += (size_t)z * 8388608;
  }

  const int tid = threadIdx.x;
  const int n0 = bx * 128;
  const int m0 = by * 128;

  const int lane = tid & 63, wid = tid >> 6;
  const int wr = wid >> 1, wc = wid & 1;
  const int fr = lane & 15, kc = lane >> 4;
  const int fsw = ((fr >> 1) & 3) << 4;

  // DMA staging geometry (see R8)
  const int seg0 = wid * 2;
  const int r0 = seg0 * 16 + (lane >> 2);
  const int r1 = r0 + 16;
  const int cp = lane & 3;
  const int c0e = (cp ^ ((r0 >> 1) & 3)) * 8;
  const int c1e = (cp ^ ((r1 >> 1) & 3)) * 8;
  char* const dA0 = sAhi + seg0 * 1024;  char* const dA1 = dA0 + 1024;
  char* const dL0 = sAlo + seg0 * 1024;  char* const dL1 = dL0 + 1024;
  char* const dB0 = sBhi + seg0 * 1024;  char* const dB1 = dB0 + 1024;
  char* const dBl0 = sBlo + seg0 * 1024; char* const dBl1 = dBl0 + 1024;

  f32x4 acc[4][4];
  #pragma unroll
  for (int i = 0; i < 4; ++i)
    #pragma unroll
    for (int j = 0; j < 4; ++j) acc[i][j] = f32x4{0.f, 0.f, 0.f, 0.f};

  for (int k0 = 0; k0 < K; k0 += 32) {
    __syncthreads();   // WAR: prior tile's ds_reads complete before DMA lands
    if constexpr (MODE == 0) {
      const int t = k0 >> 8;
      const int cb = (n0 >> 8) * 256 + (k0 & 255);
      const int g0 = m0 + r0, g1 = m0 + r1;
      int s0 = (g0 & 4095) + t - 1; s0 = s0 < 0 ? 0 : (s0 > 4095 ? 4095 : s0);
      int s1 = (g1 & 4095) + t - 1; s1 = s1 < 0 ? 0 : (s1 > 4095 ? 4095 : s1);
      const size_t o0 = ((size_t)((g0 >> 12) * 4096 + s0)) * 1024 + cb;
      const size_t o1 = ((size_t)((g1 >> 12) * 4096 + s1)) * 1024 + cb;
      gload16(Ahi + o0 + c0e, dA0);
      gload16(Ahi + o1 + c1e, dA1);
      gload16(Alo + o0 + c0e, dL0);
      gload16(Alo + o1 + c1e, dL1);
    } else {
      const size_t o0 = (size_t)(m0 + r0) * K + k0;
      const size_t o1 = (size_t)(m0 + r1) * K + k0;
      gload16(Ahi + o0 + c0e, dA0);
      gload16(Ahi + o1 + c1e, dA1);
      if constexpr (SPLIT) {
        gload16(Alo + o0 + c0e, dL0);
        gload16(Alo + o1 + c1e, dL1);
      }
    }
    {
      const size_t o0 = (size_t)(n0 + r0) * K + k0;
      const size_t o1 = (size_t)(n0 + r1) * K + k0;
      gload16(Bhig + o0 + c0e, dB0);
      gload16(Bhig + o1 + c1e, dB1);
      if constexpr (SPLIT) {
        gload16(Blog + o0 + c0e, dBl0);
        gload16(Blog + o1 + c1e, dBl1);
      }
    }
    __syncthreads();   // drains vmcnt(0): tile staged

    if constexpr (MODE == 0) {
      const int t = k0 >> 8;
      int zr = -1;
      if (t == 0 && (m0 & 4095) == 0) zr = 0;
      if (t == 2 && (m0 & 4095) == 3968) zr = 127;
      if (zr >= 0) {
        if (tid < 8) {
          char* buf = (tid < 4) ? sAhi : sAlo;
          *(s16x8*)(buf + zr * 64 + (tid & 3) * 16) = s16x8{0,0,0,0,0,0,0,0};
        }
        __syncthreads();
      }
    }

    s16x8 Af[4], Al[4], Bf[4], Bl[4];
    #pragma unroll
    for (int i = 0; i < 4; ++i) {
      const int off = (wr * 64 + i * 16 + fr) * 64 + ((kc * 16) ^ fsw);
      Af[i] = *(const s16x8*)(sAhi + off);
      if constexpr (SPLIT) Al[i] = *(const s16x8*)(sAlo + off);
    }
    #pragma unroll
    for (int j = 0; j < 4; ++j) {
      const int off = (wc * 64 + j * 16 + fr) * 64 + ((kc * 16) ^ fsw);
      Bf[j] = *(const s16x8*)(sBhi + off);
      if constexpr (SPLIT) Bl[j] = *(const s16x8*)(sBlo + off);
    }
    #pragma unroll
    for (int i = 0; i < 4; ++i)
      #pragma unroll
      for (int j = 0; j < 4; ++j) {
        acc[i][j] = __builtin_amdgcn_mfma_f32_16x16x32_bf16(Af[i], Bf[j], acc[i][j], 0, 0, 0);
        if constexpr (SPLIT) {
          acc[i][j] = __builtin_amdgcn_mfma_f32_16x16x32_bf16(Af[i], Bl[j], acc[i][j], 0, 0, 0);
          acc[i][j] = __builtin_amdgcn_mfma_f32_16x16x32_bf16(Al[i], Bf[j], acc[i][j], 0, 0, 0);
        }
      }
  }

  // ---- epilogue ----
  if constexpr (MODE == 2) {
    #pragma unroll
    for (int i = 0; i < 4; ++i)
      #pragma unroll
      for (int j2 = 0; j2 < 2; ++j2) {
        const int col0 = n0 + wc * 64 + j2 * 16 + fr;
        const int jr = col0 & 31;
        const float b0 = bias[col0], b1 = bias[col0 + 32];
        #pragma unroll
        for (int rr = 0; rr < 4; ++rr) {
          const int row = m0 + wr * 64 + i * 16 + kc * 4 + rr;
          float v0 = acc[i][j2][rr] + b0;
          float v1 = acc[i][j2 + 2][rr] + b1;
          if (z < 2) {
            const float2 cs = tab[((row & 4095) << 5) | jr];
            const float rr0 = v0 * cs.x - v1 * cs.y;
            const float rr1 = v1 * cs.x + v0 * cs.y;
            v0 = rr0; v1 = rr1;
          }
          Cf[(size_t)row * N + col0] = v0;
          Cf[(size_t)row * N + col0 + 32] = v1;
        }
      }
  } else {
    #pragma unroll
    for (int i = 0; i < 4; ++i)
      #pragma unroll
      for (int j = 0; j < 4; ++j) {
        const int col = n0 + wc * 64 + j * 16 + fr;
        #pragma unroll
        for (int rr = 0; rr < 4; ++rr) {
          const int row = m0 + wr * 64 + i * 16 + kc * 4 + rr;
          const float v = acc[i][j][rr];
          if constexpr (MODE == 0) {
            const float hv = v + bias[col];
            const unsigned short hh = f2bf(hv);
            C1[(size_t)row * N + col] = hh;
            C2[(size_t)row * N + col] = f2bf(hv - bf2f(hh));
          } else if constexpr (MODE == 1) {
            const int g = col >> 8;
            const float sg = (g == 0) ? 1.0f : ((g == 1) ? 1.41421356237309515f : 2.0f);
            const float zc = cosf(v * sg + bias[col]) * 0.08838834764831845f;
            C1[(size_t)row * N + col] = f2bf(zc);
          } else {
            Cf[(size_t)row * N + col] = v + bias[col];
          }
        }
      }
  }
}

// ======================== RoPE table ========================================
__global__ __launch_bounds__(256) void rope_table_kernel(float2* __restrict__ tab)
{
  const int idx = blockIdx.x * 256 + threadIdx.x;
  const int j = idx & 31, s = idx >> 5;
  const double inv = pow(10000.0, -(double)j * (1.0 / 32.0));
  double sd, cd;
  sincos((double)s * inv, &sd, &cd);
  tab[idx] = make_float2((float)cd, (float)sd);
}

// ======================== Nystrom RBF (MFMA) ================================
// grid 512 = 32 bh * 16 chunks(256 s); 256 thr (4 waves), wave owns 64 rows.
// kny[row, l] = exp((2 k.lm_l - |k|^2 - |lm_l|^2)/64), written as plain bf16;
// knorm[row] = 0.5 * sum_l kny^2 (pre-computed for favor_k).
__global__ __launch_bounds__(256) void nystrom_mfma(
    const float* __restrict__ Kb, const float* __restrict__ lm,
    unsigned short* __restrict__ kny, float* __restrict__ knorm)
{
  const int bid = blockIdx.x;
  const int bh = bid >> 4, chunk = bid & 15;
  const int b = bh >> 4, h = bh & 15;
  const int tid = threadIdx.x, lane = tid & 63, wid = tid >> 6;
  const int fr = lane & 15, kc = lane >> 4;
  const int ws0 = chunk * 256 + wid * 64;

  __shared__ float lnorm[64];
  if (tid < 64) {
    float s = 0.f;
    #pragma unroll
    for (int d = 0; d < 64; ++d) { const float v = lm[tid * 64 + d]; s = fmaf(v, v, s); }
    lnorm[tid] = s;
  }
  __syncthreads();

  // B frags: lm row l = c*16+fr, k-dim d = ks*32 + kc*8 .. +8
  s16x8 bfr[4][2];
  #pragma unroll
  for (int c = 0; c < 4; ++c)
    #pragma unroll
    for (int ks = 0; ks < 2; ++ks) {
      const float* lp = lm + (c * 16 + fr) * 64 + ks * 32 + kc * 8;
      #pragma unroll
      for (int u = 0; u < 8; ++u) bfr[c][ks][u] = (short)f2bf(lp[u]);
    }

  #pragma unroll
  for (int r = 0; r < 4; ++r) {
    const int s_r = ws0 + r * 16 + fr;
    const float* ap = Kb + ((size_t)(b * 4096 + s_r)) * 1024 + h * 64;
    s16x8 afr[2];
    float part = 0.f;
    #pragma unroll
    for (int ks = 0; ks < 2; ++ks) {
      const float4 f0 = *(const float4*)(ap + ks * 32 + kc * 8);
      const float4 f1 = *(const float4*)(ap + ks * 32 + kc * 8 + 4);
      const float v[8] = {f0.x, f0.y, f0.z, f0.w, f1.x, f1.y, f1.z, f1.w};
      #pragma unroll
      for (int u = 0; u < 8; ++u) {
        part = fmaf(v[u], v[u], part);
        afr[ks][u] = (short)f2bf(v[u]);
      }
    }
    part += __shfl_xor(part, 16);
    part += __shfl_xor(part, 32);       // |k|^2 of row (this lane's fr-row)

    float sq[4] = {0.f, 0.f, 0.f, 0.f}; // per-reg partial sum of kny^2
    #pragma unroll
    for (int c = 0; c < 4; ++c) {
      f32x4 acc = f32x4{0.f, 0.f, 0.f, 0.f};
      acc = __builtin_amdgcn_mfma_f32_16x16x32_bf16(afr[0], bfr[c][0], acc, 0, 0, 0);
      acc = __builtin_amdgcn_mfma_f32_16x16x32_bf16(afr[1], bfr[c][1], acc, 0, 0, 0);
      const float ln = lnorm[c * 16 + fr];
      #pragma unroll
      for (int reg = 0; reg < 4; ++reg) {
        const float nk = __shfl(part, kc * 4 + reg);
        const float val = __expf((2.f * acc[reg] - nk - ln) * 0.015625f);
        sq[reg] = fmaf(val, val, sq[reg]);
        const int srow = ws0 + r * 16 + kc * 4 + reg;
        kny[((size_t)(b * 4096 + srow) * 16 + h) * 64 + c * 16 + fr] = f2bf(val);
      }
    }
    #pragma unroll
    for (int reg = 0; reg < 4; ++reg) {
      float s2 = sq[reg];
      s2 += __shfl_xor(s2, 1); s2 += __shfl_xor(s2, 2);
      s2 += __shfl_xor(s2, 4); s2 += __shfl_xor(s2, 8);
      if (fr == 0) {
        const int srow = ws0 + r * 16 + kc * 4 + reg;
        knorm[(size_t)(b * 4096 + srow) * 16 + h] = 0.5f * s2;
      }
    }
  }
}

// ======================== FAVOR-K (MFMA, single-term) =======================
__global__ __launch_bounds__(512) void favor_k_mfma(
    const unsigned short* __restrict__ kny, const float* __restrict__ knorm,
    const unsigned short* __restrict__ oThi,
    const unsigned short* __restrict__ VT, float* __restrict__ KVp)
{
  const int bid = blockIdx.x;
  const int bh = bid >> 3, chunk = bid & 7;
  const int b = bh >> 4, h = bh & 15;
  const int s0 = chunk * 512;
  const int tid = threadIdx.x, lane = tid & 63, wid = tid >> 6;
  const int fr = lane & 15, kc = lane >> 4;
  const int m0w = wid * 32;

  __shared__ unsigned short P[256][40];
  __shared__ float T[8][32][84];

  s16x8 whi[2][2];
  #pragma unroll
  for (int c = 0; c < 2; ++c)
    #pragma unroll
    for (int ks = 0; ks < 2; ++ks)
      whi[c][ks] = *(const s16x8*)(oThi + (size_t)(m0w + c * 16 + fr) * 64 + ks * 32 + kc * 8);

  f32x4 acc2[2][5];
  #pragma unroll
  for (int i = 0; i < 2; ++i)
    #pragma unroll
    for (int j = 0; j < 5; ++j) acc2[i][j] = f32x4{0.f, 0.f, 0.f, 0.f};

  for (int st = 0; st < 512; st += 32) {
    s16x8 a1[2][2];
    float nrm[2];
    #pragma unroll
    for (int r = 0; r < 2; ++r) {
      const size_t kidx = (size_t)(b * 4096 + s0 + st + r * 16 + fr) * 16 + h;
      a1[r][0] = *(const s16x8*)(kny + kidx * 64 + kc * 8);
      a1[r][1] = *(const s16x8*)(kny + kidx * 64 + 32 + kc * 8);
      nrm[r] = knorm[kidx];
    }
    __syncthreads();
    #pragma unroll
    for (int r = 0; r < 2; ++r)
      #pragma unroll
      for (int c = 0; c < 2; ++c) {
        f32x4 s1 = f32x4{0.f, 0.f, 0.f, 0.f};
        s1 = __builtin_amdgcn_mfma_f32_16x16x32_bf16(a1[r][0], whi[c][0], s1, 0, 0, 0);
        s1 = __builtin_amdgcn_mfma_f32_16x16x32_bf16(a1[r][1], whi[c][1], s1, 0, 0, 0);
        #pragma unroll
        for (int reg = 0; reg < 4; ++reg) {
          const int sl = kc * 4 + reg;
          const float nn = __shfl(nrm[r], sl);
          const float p = __expf(s1[reg] - nn - 2.772588722239781f);
          P[m0w + c * 16 + fr][r * 16 + sl] = f2bf(p);
        }
      }
    __syncthreads();
    s16x8 b2[5];
    #pragma unroll
    for (int nf = 0; nf < 5; ++nf)
      b2[nf] = *(const s16x8*)(VT + ((size_t)bh * 80 + nf * 16 + fr) * 4096 +
                               s0 + st + kc * 8);
    #pragma unroll
    for (int mf = 0; mf < 2; ++mf) {
      const s16x8 a2 = *(const s16x8*)&P[m0w + mf * 16 + fr][kc * 8];
      #pragma unroll
      for (int nf = 0; nf < 5; ++nf)
        acc2[mf][nf] = __builtin_amdgcn_mfma_f32_16x16x32_bf16(a2, b2[nf], acc2[mf][nf], 0, 0, 0);
    }
  }
  #pragma unroll
  for (int mf = 0; mf < 2; ++mf)
    #pragma unroll
    for (int nf = 0; nf < 5; ++nf)
      #pragma unroll
      for (int reg = 0; reg < 4; ++reg)
        T[wid][mf * 16 + kc * 4 + reg][nf * 16 + fr] = acc2[mf][nf][reg];
  __syncthreads();
  #pragma unroll
  for (int i = 0; i < 40; ++i) {
    const int flat = i * 64 + lane;
    const int n = flat >> 5, ml = flat & 31;
    KVp[((size_t)bid * 80 + n) * 256 + m0w + ml] = T[wid][ml][n];
  }
}

// ======================== reduce KVp -> KVXT bf16 ===========================
__global__ __launch_bounds__(256) void reduce_kvxt_kernel(
    const float* __restrict__ KVp, unsigned short* __restrict__ KVXT)
{
  const int bh = blockIdx.x;
  const int m = threadIdx.x;
  for (int n = 0; n < 80; ++n) {
    float s = 0.f;
    #pragma unroll
    for (int c = 0; c < 8; ++c)
      s += KVp[((size_t)(bh * 8 + c) * 80 + n) * 256 + m];
    KVXT[((size_t)bh * 80 + n) * 256 + m] = f2bf(s);
  }
}

// ======================== FAVOR-Q (MFMA, single-term) =======================
__global__ __launch_bounds__(512) void favor_q_mfma(
    const float* __restrict__ Q, const unsigned short* __restrict__ oThi,
    const unsigned short* __restrict__ KVXT, unsigned short* __restrict__ O)
{
  const int bid = blockIdx.x;
  const int bh = bid >> 4, chunk = bid & 15;
  const int b = bh >> 4, h = bh & 15;
  const int s0 = chunk * 256;
  const int tid = threadIdx.x, lane = tid & 63, wid = tid >> 6;
  const int fr = lane & 15, kc = lane >> 4;
  const int ws0 = s0 + wid * 32;

  __shared__ unsigned short KX[80][264];
  __shared__ unsigned short P[8][32][66];

  for (int i = tid; i < 80 * 256; i += 512)
    KX[i >> 8][i & 255] = KVXT[(size_t)bh * 80 * 256 + i];
  __syncthreads();

  s16x8 ahi[2][2];
  float nrm[2];
  #pragma unroll
  for (int r = 0; r < 2; ++r) {
    float part = 0.f;
    #pragma unroll
    for (int ks = 0; ks < 2; ++ks) {
      const float* ap = Q + ((size_t)(b * 4096 + ws0 + r * 16 + fr)) * 1024 +
                        h * 64 + ks * 32 + kc * 8;
      const float4 f0 = ((const float4*)ap)[0];
      const float4 f1 = ((const float4*)ap)[1];
      const float v[8] = {f0.x, f0.y, f0.z, f0.w, f1.x, f1.y, f1.z, f1.w};
      #pragma unroll
      for (int u = 0; u < 8; ++u) {
        part = fmaf(v[u], v[u], part);
        ahi[r][ks][u] = (short)f2bf(v[u]);
      }
    }
    part += __shfl_xor(part, 16);
    part += __shfl_xor(part, 32);
    nrm[r] = 0.5f * part;
  }

  f32x4 acc2[2][5];
  #pragma unroll
  for (int i = 0; i < 2; ++i)
    #pragma unroll
    for (int j = 0; j < 5; ++j) acc2[i][j] = f32x4{0.f, 0.f, 0.f, 0.f};

  for (int mc = 0; mc < 4; ++mc) {
    __syncthreads();
    #pragma unroll
    for (int r = 0; r < 2; ++r)
      #pragma unroll
      for (int c = 0; c < 4; ++c) {
        f32x4 s1 = f32x4{0.f, 0.f, 0.f, 0.f};
        #pragma unroll
        for (int ks = 0; ks < 2; ++ks) {
          const size_t off = (size_t)(mc * 64 + c * 16 + fr) * 64 + ks * 32 + kc * 8;
          const s16x8 bh1 = *(const s16x8*)(oThi + off);
          s1 = __builtin_amdgcn_mfma_f32_16x16x32_bf16(ahi[r][ks], bh1, s1, 0, 0, 0);
        }
        #pragma unroll
        for (int reg = 0; reg < 4; ++reg) {
          const int sl = kc * 4 + reg;
          const float nn = __shfl(nrm[r], sl);
          const float p = __expf(s1[reg] - nn - 2.772588722239781f);
          P[wid][r * 16 + sl][c * 16 + fr] = f2bf(p);
        }
      }
    __syncthreads();
    #pragma unroll
    for (int ks2 = 0; ks2 < 2; ++ks2) {
      s16x8 b2[5];
      #pragma unroll
      for (int nf = 0; nf < 5; ++nf)
        b2[nf] = *(const s16x8*)&KX[nf * 16 + fr][mc * 64 + ks2 * 32 + kc * 8];
      #pragma unroll
      for (int r = 0; r < 2; ++r) {
        const s16x8 a2 = *(const s16x8*)&P[wid][r * 16 + fr][ks2 * 32 + kc * 8];
        #pragma unroll
        for (int nf = 0; nf < 5; ++nf)
          acc2[r][nf] = __builtin_amdgcn_mfma_f32_16x16x32_bf16(a2, b2[nf], acc2[r][nf], 0, 0, 0);
      }
    }
  }
  #pragma unroll
  for (int r = 0; r < 2; ++r)
    #pragma unroll
    for (int reg = 0; reg < 4; ++reg) {
      const int s = ws0 + r * 16 + kc * 4 + reg;
      const float dv = __shfl(acc2[r][4][reg], lane & 48) + 1e-6f;
      #pragma unroll
      for (int nf = 0; nf < 4; ++nf)
        O[(size_t)(b * 4096 + s) * 1024 + h * 64 + nf * 16 + fr] =
            f2bf(acc2[r][nf][reg] / dv);
    }
}

// ======================== launcher ==========================================
extern "C" void kernel_launch(void* const* d_in, const int* in_sizes, int n_in,
                              void* d_out, int out_size, void* d_ws, size_t ws_size,
                              hipStream_t stream)
{
  const float* x      = (const float*)d_in[0];
  const float* conv_k = (const float*)d_in[1];
  const float* conv_b = (const float*)d_in[2];
  const float* rff_w  = (const float*)d_in[3];
  const float* rff_b  = (const float*)d_in[4];
  const float* proj_w = (const float*)d_in[5];
  const float* proj_b = (const float*)d_in[6];
  const float* omega  = (const float*)d_in[7];
  const float* lm     = (const float*)d_in[8];
  const float* out_w  = (const float*)d_in[9];
  const float* out_b  = (const float*)d_in[10];

  char* wsb = (char*)d_ws;
  size_t o = 0;
  auto alloc = [&](size_t bytes) {
    char* p = wsb + o;
    o = (o + bytes + 255) & ~(size_t)255;
    return p;
  };
  // --- region A: persistent (weights/tables)
  unsigned short* Wc_hi = (unsigned short*)alloc(4718592);
  unsigned short* Wc_lo = (unsigned short*)alloc(4718592);
  unsigned short* Wr_hi = (unsigned short*)alloc(4718592);
  unsigned short* Wr_lo = (unsigned short*)alloc(4718592);
  unsigned short* Wp    = (unsigned short*)alloc(4718592);
  unsigned short* Wo    = (unsigned short*)alloc(2097152);
  unsigned short* oThi  = (unsigned short*)alloc(32768);
  unsigned short* oTlo  = (unsigned short*)alloc(32768);   // unused (kept for layout)
  float2* tab           = (float2*)alloc(1048576);
  // --- region B: xhi/xlo -> feats -> {VT, Obf, KVXT}
  char* RB = alloc(41943040);
  unsigned short* xhi   = (unsigned short*)RB;
  unsigned short* xlo   = (unsigned short*)(RB + 16777216);
  unsigned short* feats = (unsigned short*)RB;
  unsigned short* VT    = (unsigned short*)RB;
  unsigned short* Obf   = (unsigned short*)(RB + 20971520);
  unsigned short* KVXT  = (unsigned short*)(RB + 37748736);
  // --- region C: h hi/lo (3x) -> QKV f32 (3x)
  char* RC = alloc(100663296);
  unsigned short* hhi   = (unsigned short*)RC;
  unsigned short* hlo   = (unsigned short*)(RC + 50331648);
  float* QKV            = (float*)RC;
  // --- region E: kny bf16 (16.8MB) + knorm (0.5MB, in old kny-lo half) + KVp
  char* RE = alloc(33554432);
  unsigned short* knyb  = (unsigned short*)RE;
  float* knorm          = (float*)(RE + 16777216);
  float* KVp = (float*)alloc(20971520);
  (void)oTlo; (void)ws_size;

  dim3 blk(256);
  split_prep_kernel<<<4096, blk, 0, stream>>>(x, xhi, xlo, 1048576);
  wconv_kernel<0><<<dim3(12, 16, 3), blk, 0, stream>>>(conv_k, Wc_hi, Wc_lo);
  wconv_kernel<1><<<dim3(16, 4, 9),  blk, 0, stream>>>(rff_w, Wr_hi, Wr_lo);
  wconv_kernel<2><<<dim3(12, 16, 3), blk, 0, stream>>>(proj_w, Wp, nullptr);
  wconv_kernel<3><<<dim3(16, 16, 1), blk, 0, stream>>>(out_w, Wo, nullptr);
  omega_prep_kernel<<<64, blk, 0, stream>>>(omega, oThi);
  rope_table_kernel<<<512, blk, 0, stream>>>(tab);

  gemm_mfma<0><<<dim3(8, 64, 3), blk, 0, stream>>>(
      xhi, xlo, Wc_hi, Wc_lo, conv_b, nullptr,
      nullptr, hhi, hlo, 8192, 1024, 768);
  gemm_mfma<1><<<dim3(6, 64, 3), blk, 0, stream>>>(
      hhi, hlo, Wr_hi, Wr_lo, rff_b, nullptr,
      nullptr, feats, nullptr, 8192, 768, 1024);
  gemm_mfma<2><<<dim3(8, 64, 3), blk, 0, stream>>>(
      feats, nullptr, Wp, nullptr, proj_b, tab,
      QKV, nullptr, nullptr, 8192, 1024, 768);

  float* Qb = QKV;
  float* Kb = QKV + 8388608;
  float* Vb = QKV + 16777216;
  vt_kernel<<<dim3(32, 64), blk, 0, stream>>>(Vb, VT);
  nystrom_mfma<<<512, blk, 0, stream>>>(Kb, lm, knyb, knorm);
  favor_k_mfma<<<256, dim3(512), 0, stream>>>(knyb, knorm, oThi, VT, KVp);
  reduce_kvxt_kernel<<<32, blk, 0, stream>>>(KVp, KVXT);
  favor_q_mfma<<<512, dim3(512), 0, stream>>>(Qb, oThi, KVXT, Obf);
  gemm_mfma<3><<<dim3(8, 64), blk, 0, stream>>>(
      Obf, nullptr, Wo, nullptr, out_b, nullptr,
      (float*)d_out, nullptr, nullptr, 8192, 1024, 1024);
}